// Round 2
// baseline (825.061 us; speedup 1.0000x reference)
//
#include <hip/hip_runtime.h>
#include <hip/hip_bf16.h>
#include <cstdint>
#include <cstddef>

typedef __hip_bfloat16 BF;
typedef __attribute__((ext_vector_type(8))) short bhalf8;   // 8 bf16 (MFMA A/B frag)
typedef __attribute__((ext_vector_type(4))) float floatx4;  // MFMA C/D frag

#define NB 8
#define NC 512
#define NHW 4096
#define NG 32

__device__ __forceinline__ float b2f(short h) {
    union { unsigned u; float f; } c;
    c.u = ((unsigned)(unsigned short)h) << 16;
    return c.f;
}
__device__ __forceinline__ short f2b(float f) {
    __hip_bfloat16 h = __float2bfloat16(f);
    short s;
    __builtin_memcpy(&s, &h, 2);
    return s;
}

// 16B global -> LDS direct (wave-uniform LDS base + lane*16)
__device__ __forceinline__ void gload16(const BF* g, BF* l) {
    __builtin_amdgcn_global_load_lds(
        (const __attribute__((address_space(1))) void*)g,
        (__attribute__((address_space(3))) void*)l, 16, 0, 0);
}

__device__ __forceinline__ void BARRIER() {
    asm volatile("" ::: "memory");
    __builtin_amdgcn_s_barrier();
    asm volatile("" ::: "memory");
}
#define WAITVM(N) asm volatile("s_waitcnt vmcnt(" #N ")" ::: "memory")
#define WAITLGKM() asm volatile("s_waitcnt lgkmcnt(0)" ::: "memory")

// T1: bijective XCD-aware tile swizzle (nwg % 8 == 0 for all our grids)
__device__ __forceinline__ void xcd_swizzle(int& bx, int& by) {
    const int gx = gridDim.x;
    const int nwg = gx * gridDim.y;
    if ((nwg & 7) == 0) {
        const int lin = by * gx + bx;
        const int cpx = nwg >> 3;
        const int s = (lin & 7) * cpx + (lin >> 3);
        bx = s % gx;
        by = s / gx;
    }
}

// ---------------------------------------------------------------------------
__global__ __launch_bounds__(256) void f2b_convert4(const float* __restrict__ s0,
                                                    const float* __restrict__ s1,
                                                    const float* __restrict__ s2,
                                                    const float* __restrict__ s3,
                                                    BF* __restrict__ dst) {
    const int which = blockIdx.x >> 8;
    const float* src = (which == 0) ? s0 : (which == 1) ? s1 : (which == 2) ? s2 : s3;
    BF* d = dst + (long)which * (NC * NC);
    const int i = ((blockIdx.x & 255) * 256 + threadIdx.x) * 4;
    float4 v = *(const float4*)&src[i];
    d[i]     = __float2bfloat16(v.x);
    d[i + 1] = __float2bfloat16(v.y);
    d[i + 2] = __float2bfloat16(v.z);
    d[i + 3] = __float2bfloat16(v.w);
}

// ---------------------------------------------------------------------------
__global__ __launch_bounds__(256) void gn_stats(const float* __restrict__ x,
                                                float* __restrict__ stats) {
    const int bg = blockIdx.x;
    const long base = (long)bg * 65536;
    float s = 0.f, q = 0.f;
    for (int i = threadIdx.x * 4; i < 65536; i += 256 * 4) {
        float4 v4 = *(const float4*)&x[base + i];
        s += v4.x + v4.y + v4.z + v4.w;
        q += v4.x * v4.x + v4.y * v4.y + v4.z * v4.z + v4.w * v4.w;
    }
#pragma unroll
    for (int o = 32; o; o >>= 1) { s += __shfl_down(s, o); q += __shfl_down(q, o); }
    __shared__ float rs[4], rq[4];
    const int w = threadIdx.x >> 6;
    if ((threadIdx.x & 63) == 0) { rs[w] = s; rq[w] = q; }
    __syncthreads();
    if (threadIdx.x == 0) {
        s = rs[0] + rs[1] + rs[2] + rs[3];
        q = rq[0] + rq[1] + rq[2] + rq[3];
        float mean = s * (1.f / 65536.f);
        float var = q * (1.f / 65536.f) - mean * mean;
        stats[2 * bg]     = mean;
        stats[2 * bg + 1] = rsqrtf(fmaxf(var, 0.f) + 1e-6f);
    }
}

// ---------------------------------------------------------------------------
__global__ __launch_bounds__(256) void gn_apply(const float* __restrict__ x,
                                                const float* __restrict__ gamma,
                                                const float* __restrict__ beta,
                                                const float* __restrict__ stats,
                                                BF* __restrict__ n) {
    __shared__ float tile[64][65];
    const int b = blockIdx.z, c0 = blockIdx.y * 64, s0 = blockIdx.x * 64;
    const long xbase = ((long)b * NC + c0) * NHW + s0;
#pragma unroll
    for (int i = 0; i < 16; i++) {
        int lin = i * 256 + threadIdx.x;
        int cl = lin >> 6, sl = lin & 63;
        int c = c0 + cl;
        float2 mr = ((const float2*)stats)[b * NG + (c >> 4)];
        float v = x[xbase + (long)cl * NHW + sl];
        v = (v - mr.x) * mr.y * gamma[c] + beta[c];
        tile[cl][sl] = v;
    }
    __syncthreads();
    const long nbase = ((long)b * NHW + s0) * NC + c0;
#pragma unroll
    for (int i = 0; i < 16; i++) {
        int lin = i * 256 + threadIdx.x;
        int sl = lin >> 6, cl = lin & 63;
        n[nbase + (long)sl * NC + cl] = __float2bfloat16(tile[cl][sl]);
    }
}

// ---------------------------------------------------------------------------
// 256x256 8-phase GEMM (T1+T2+T3+T4+T5). C[m][n] = scale*sum_k A[m][k]*B[n][k]
// (+bias[n]). A [M,K], B [N,K] K-contig bf16, lda=ldb=K. BK=64, 8 waves (2Mx4N),
// each 128x64 out. LDS 128KB: 2 dbuf x {A0,A1,B0,B1} 16KB regions, st_16x32
// XOR swizzle (byte ^= ((byte>>9)&1)<<5) via pre-swizzled global source.
// Counted vmcnt(6) at phases 4/8 keeps 3 half-tiles in flight across barriers.
// ---------------------------------------------------------------------------
#define LDA8(buf, mf, ks) (*(const bhalf8*)(sL + (buf) * 65536 + aOff + (mf) * 2048 + (ks) * 64))
#define LDB8(buf, nf, ks) (*(const bhalf8*)(sL + (buf) * 65536 + bOff + (nf) * 2048 + (ks) * 64))
#define QUAD(M0, N0)                                                                     \
    {                                                                                    \
        _Pragma("unroll") for (int mf = (M0); mf < (M0) + 4; mf++)                       \
            _Pragma("unroll") for (int nf = (N0); nf < (N0) + 2; nf++) {                 \
            acc[mf][nf] = __builtin_amdgcn_mfma_f32_16x16x32_bf16(                       \
                aR[mf & 3][0], bR[nf][0], acc[mf][nf], 0, 0, 0);                         \
            acc[mf][nf] = __builtin_amdgcn_mfma_f32_16x16x32_bf16(                       \
                aR[mf & 3][1], bR[nf][1], acc[mf][nf], 0, 0, 0);                         \
        }                                                                                \
    }

template <bool BIAS, bool TRANS, bool RESID>
__global__ __launch_bounds__(512) void gemm256(
    const BF* __restrict__ A, long aStride,
    const BF* __restrict__ Bm, long bStride,
    BF* __restrict__ C, long cStride,
    const float* __restrict__ bias,
    const float* __restrict__ resid, float* __restrict__ outF,
    int M, int N, int K, float scale)
{
    __shared__ __align__(16) char sL[131072];
    const int tid = threadIdx.x;
    const int wave = tid >> 6, lane = tid & 63;
    int bxi = blockIdx.x, byi = blockIdx.y;
    xcd_swizzle(bxi, byi);
    const int bm = byi * 256, bn = bxi * 256;
    const BF* Ab = A + (long)blockIdx.z * aStride + (long)bm * K;
    const BF* Bb = Bm + (long)blockIdx.z * bStride + (long)bn * K;

    // staging: LDS dest is linear (j*8192 + tid*16); global source pre-swizzled
    const int d0 = tid * 16, d1 = 8192 + tid * 16;
    const int p0 = d0 ^ (((d0 >> 9) & 1) << 5);
    const int p1 = d1 ^ (((d1 >> 9) & 1) << 5);
    const int soff0 = (p0 >> 7) * K + ((p0 & 127) >> 1);
    const int soff1 = (p1 >> 7) * K + ((p1 & 127) >> 1);
    const int lds0 = wave * 1024;           // wave-uniform; HW adds lane*16
    const int lds1 = 8192 + wave * 1024;

    // frag ds_read offsets (swizzle folds to a lane-constant bit-5 XOR)
    const int lr = lane & 15, lk2 = (lane >> 4) * 16;
    const int sbase = (lr * 128 + lk2) ^ (((lr >> 2) & 1) << 5);
    const int aOff = (wave >> 2) * 16384 + sbase;                       // A region
    const int bOff = (2 + ((wave >> 1) & 1)) * 16384 + (wave & 1) * 8192 + sbase;

    auto STAGE = [&](int t, int region, int dbuf) {
        const BF* g = ((region < 2) ? (Ab + (long)region * 128 * K)
                                    : (Bb + (long)(region - 2) * 128 * K)) + (long)t * 64;
        char* lb = sL + dbuf * 65536 + region * 16384;
        gload16(g + soff0, (BF*)(lb + lds0));
        gload16(g + soff1, (BF*)(lb + lds1));
    };

    floatx4 acc[8][4];
#pragma unroll
    for (int i = 0; i < 8; i++)
#pragma unroll
        for (int j = 0; j < 4; j++) acc[i][j] = (floatx4){0.f, 0.f, 0.f, 0.f};

    const int nt = K >> 6, ngrp = nt >> 1;

    // prologue: T0 full + T1.{B0,B1,A0}; T0 guaranteed landed
    STAGE(0, 0, 0); STAGE(0, 1, 0); STAGE(0, 2, 0); STAGE(0, 3, 0);
    WAITVM(4);
    STAGE(1, 2, 1); STAGE(1, 3, 1); STAGE(1, 0, 1);
    WAITVM(6);
    BARRIER();

    bhalf8 aR[4][2], bR[4][2];

    for (int g = 0; g < ngrp; ++g) {
        const bool st = (g < ngrp - 1);
        const int t2 = 2 * g + 2, t3 = 2 * g + 3;

        // ---- phase 1 (tile 2g, buf0): A mf0-3, B nf0-1 (+nf2-3 for B0 waves)
#pragma unroll
        for (int mf = 0; mf < 4; mf++) { aR[mf][0] = LDA8(0, mf, 0); aR[mf][1] = LDA8(0, mf, 1); }
#pragma unroll
        for (int nf = 0; nf < 2; nf++) { bR[nf][0] = LDB8(0, nf, 0); bR[nf][1] = LDB8(0, nf, 1); }
        if (!(wave & 2)) {
#pragma unroll
            for (int nf = 2; nf < 4; nf++) { bR[nf][0] = LDB8(0, nf, 0); bR[nf][1] = LDB8(0, nf, 1); }
        }
        STAGE(2 * g + 1, 1, 1);          // T(2g+1).A1 -> buf1 (region free since prev ph7)
        BARRIER(); WAITLGKM();
        __builtin_amdgcn_s_setprio(1);
        QUAD(0, 0);
        __builtin_amdgcn_s_setprio(0);
        BARRIER();

        // ---- phase 2: B1-waves read nf2-3; stage T2.B0 (buf0.B0 last read ph1)
        if (wave & 2) {
#pragma unroll
            for (int nf = 2; nf < 4; nf++) { bR[nf][0] = LDB8(0, nf, 0); bR[nf][1] = LDB8(0, nf, 1); }
        }
        if (st) STAGE(t2, 2, 0);
        BARRIER(); WAITLGKM();
        __builtin_amdgcn_s_setprio(1);
        QUAD(0, 2);
        __builtin_amdgcn_s_setprio(0);
        BARRIER();

        // ---- phase 3: A mf4-7; stage T2.B1 (buf0.B1 last read ph2)
#pragma unroll
        for (int mf = 4; mf < 8; mf++) { aR[mf & 3][0] = LDA8(0, mf, 0); aR[mf & 3][1] = LDA8(0, mf, 1); }
        if (st) STAGE(t2, 3, 0);
        BARRIER(); WAITLGKM();
        __builtin_amdgcn_s_setprio(1);
        QUAD(4, 0);
        __builtin_amdgcn_s_setprio(0);
        BARRIER();

        // ---- phase 4: stage T2.A0 (buf0.A0 last read ph3); boundary vmcnt
        if (st) STAGE(t2, 0, 0);
        BARRIER();
        __builtin_amdgcn_s_setprio(1);
        QUAD(4, 2);
        __builtin_amdgcn_s_setprio(0);
        if (st) { WAITVM(6); } else { WAITVM(0); }
        BARRIER();

        // ---- phase 5 (tile 2g+1, buf1): stage T2.A1 (buf0.A1 last read ph3)
#pragma unroll
        for (int mf = 0; mf < 4; mf++) { aR[mf][0] = LDA8(1, mf, 0); aR[mf][1] = LDA8(1, mf, 1); }
#pragma unroll
        for (int nf = 0; nf < 2; nf++) { bR[nf][0] = LDB8(1, nf, 0); bR[nf][1] = LDB8(1, nf, 1); }
        if (!(wave & 2)) {
#pragma unroll
            for (int nf = 2; nf < 4; nf++) { bR[nf][0] = LDB8(1, nf, 0); bR[nf][1] = LDB8(1, nf, 1); }
        }
        if (st) STAGE(t2, 1, 0);
        BARRIER(); WAITLGKM();
        __builtin_amdgcn_s_setprio(1);
        QUAD(0, 0);
        __builtin_amdgcn_s_setprio(0);
        BARRIER();

        // ---- phase 6: stage T3.B0 (buf1.B0 last read ph5)
        if (wave & 2) {
#pragma unroll
            for (int nf = 2; nf < 4; nf++) { bR[nf][0] = LDB8(1, nf, 0); bR[nf][1] = LDB8(1, nf, 1); }
        }
        if (st) STAGE(t3, 2, 1);
        BARRIER(); WAITLGKM();
        __builtin_amdgcn_s_setprio(1);
        QUAD(0, 2);
        __builtin_amdgcn_s_setprio(0);
        BARRIER();

        // ---- phase 7: stage T3.B1 (buf1.B1 last read ph6)
#pragma unroll
        for (int mf = 4; mf < 8; mf++) { aR[mf & 3][0] = LDA8(1, mf, 0); aR[mf & 3][1] = LDA8(1, mf, 1); }
        if (st) STAGE(t3, 3, 1);
        BARRIER(); WAITLGKM();
        __builtin_amdgcn_s_setprio(1);
        QUAD(4, 0);
        __builtin_amdgcn_s_setprio(0);
        BARRIER();

        // ---- phase 8: stage T3.A0 (buf1.A0 last read ph7); boundary vmcnt
        if (st) STAGE(t3, 0, 1);
        BARRIER();
        __builtin_amdgcn_s_setprio(1);
        QUAD(4, 2);
        __builtin_amdgcn_s_setprio(0);
        if (st) { WAITVM(6); }
        BARRIER();
    }

    // ---- epilogue
    const int wm = (wave >> 2) * 128, wn = (wave & 3) * 64;
    if (RESID) {
        float* Ob = outF + (long)blockIdx.z * cStride;
        const float* Xb = resid + (long)blockIdx.z * cStride;
#pragma unroll
        for (int nf = 0; nf < 4; nf++) {
            const int col = bn + wn + nf * 16 + lr;
#pragma unroll
            for (int mf = 0; mf < 8; mf++) {
                const int row0 = bm + wm + mf * 16 + (lane >> 4) * 4;
                const long a = (long)col * M + row0;
                float4 xv = *(const float4*)&Xb[a];
                float4 ov;
                ov.x = acc[mf][nf][0] * scale + xv.x;
                ov.y = acc[mf][nf][1] * scale + xv.y;
                ov.z = acc[mf][nf][2] * scale + xv.z;
                ov.w = acc[mf][nf][3] * scale + xv.w;
                *(float4*)&Ob[a] = ov;
            }
        }
        return;
    }
    BF* Cb = C + (long)blockIdx.z * cStride;
#pragma unroll
    for (int nf = 0; nf < 4; nf++) {
        const int col = bn + wn + nf * 16 + lr;
        const float bv = BIAS ? bias[col] : 0.0f;
#pragma unroll
        for (int mf = 0; mf < 8; mf++) {
            const int row0 = bm + wm + mf * 16 + (lane >> 4) * 4;
#pragma unroll
            for (int r = 0; r < 4; r++) {
                float v = acc[mf][nf][r] * scale + bv;
                if (TRANS) Cb[(long)col * M + row0 + r] = __float2bfloat16(v);
                else       Cb[(long)(row0 + r) * N + col] = __float2bfloat16(v);
            }
        }
    }
}

// ---------------------------------------------------------------------------
// GEMM 128x128 tile, BK=32 (m97-style) — fallback for PV at chunk==2.
// ---------------------------------------------------------------------------
template <bool BIAS, bool TRANS>
__global__ __launch_bounds__(256, 2) void gemm128(
    const BF* __restrict__ A, long aStride,
    const BF* __restrict__ Bm, long bStride,
    BF* __restrict__ C, long cStride,
    const float* __restrict__ bias,
    int M, int N, int K, float scale)
{
    __shared__ __align__(16) BF sA[128 * 32];
    __shared__ __align__(16) BF sB[128 * 32];
    const int tid = threadIdx.x;
    const int wave = tid >> 6, lane = tid & 63;
    int bxi = blockIdx.x, byi = blockIdx.y;
    xcd_swizzle(bxi, byi);
    const int bm = byi * 128, bn = bxi * 128;
    const BF* Ab = A + (long)blockIdx.z * aStride + (long)bm * K;
    const BF* Bb = Bm + (long)blockIdx.z * bStride + (long)bn * K;

    const int srow = wave * 32 + (lane >> 2);
    const int sk = (lane & 3) * 8;
    const BF* gA0 = Ab + (long)srow * K + sk;
    const BF* gA1 = gA0 + (long)16 * K;
    const BF* gB0 = Bb + (long)srow * K + sk;
    const BF* gB1 = gB0 + (long)16 * K;
    BF* lA0 = &sA[(wave * 32) * 32];
    BF* lA1 = &sA[(wave * 32 + 16) * 32];
    BF* lB0 = &sB[(wave * 32) * 32];
    BF* lB1 = &sB[(wave * 32 + 16) * 32];

    floatx4 acc[4][4];
#pragma unroll
    for (int i = 0; i < 4; i++)
#pragma unroll
        for (int j = 0; j < 4; j++) acc[i][j] = (floatx4){0.f, 0.f, 0.f, 0.f};

    const int wm = (wave >> 1) * 64, wn = (wave & 1) * 64;
    const int lr = lane & 15, lk = (lane >> 4) * 8;

    for (int k0 = 0; k0 < K; k0 += 32) {
        __syncthreads();
        gload16(gA0 + k0, lA0);
        gload16(gA1 + k0, lA1);
        gload16(gB0 + k0, lB0);
        gload16(gB1 + k0, lB1);
        __syncthreads();
        bhalf8 af[4], bfr[4];
#pragma unroll
        for (int i = 0; i < 4; i++)
            af[i] = *(const bhalf8*)&sA[(wm + i * 16 + lr) * 32 + lk];
#pragma unroll
        for (int i = 0; i < 4; i++)
            bfr[i] = *(const bhalf8*)&sB[(wn + i * 16 + lr) * 32 + lk];
#pragma unroll
        for (int mi = 0; mi < 4; mi++)
#pragma unroll
            for (int ni = 0; ni < 4; ni++)
                acc[mi][ni] = __builtin_amdgcn_mfma_f32_16x16x32_bf16(
                    af[mi], bfr[ni], acc[mi][ni], 0, 0, 0);
    }

    BF* Cb = C + (long)blockIdx.z * cStride;
#pragma unroll
    for (int ni = 0; ni < 4; ni++) {
        const int col = bn + wn + ni * 16 + lr;
        const float bv = BIAS ? bias[col] : 0.0f;
#pragma unroll
        for (int mi = 0; mi < 4; mi++) {
            const int row0 = bm + wm + mi * 16 + (lane >> 4) * 4;
#pragma unroll
            for (int r = 0; r < 4; r++) {
                float v = acc[mi][ni][r] * scale + bv;
                if (TRANS) Cb[(long)col * M + row0 + r] = __float2bfloat16(v);
                else       Cb[(long)(row0 + r) * N + col] = __float2bfloat16(v);
            }
        }
    }
}

// ---------------------------------------------------------------------------
// GEMM 64(M)x128(N) tile — fallback for PV at chunk==1.
// ---------------------------------------------------------------------------
__global__ __launch_bounds__(256, 2) void gemm64(
    const BF* __restrict__ A, long aStride,
    const BF* __restrict__ Bm, long bStride,
    BF* __restrict__ C, long cStride,
    int N, int K, float scale)
{
    __shared__ __align__(16) BF sA[64 * 32];
    __shared__ __align__(16) BF sB[128 * 32];
    const int tid = threadIdx.x;
    const int wave = tid >> 6, lane = tid & 63;
    int bxi = blockIdx.x, byi = blockIdx.y;
    xcd_swizzle(bxi, byi);
    const int bm = byi * 64, bn = bxi * 128;
    const BF* Ab = A + (long)blockIdx.z * aStride + (long)bm * K;
    const BF* Bb = Bm + (long)blockIdx.z * bStride + (long)bn * K;

    const int rowoff = lane >> 2, sk = (lane & 3) * 8;
    const BF* gA0 = Ab + (long)(wave * 16 + rowoff) * K + sk;
    const BF* gB0 = Bb + (long)(wave * 32 + rowoff) * K + sk;
    const BF* gB1 = gB0 + (long)16 * K;
    BF* lA0 = &sA[(wave * 16) * 32];
    BF* lB0 = &sB[(wave * 32) * 32];
    BF* lB1 = &sB[(wave * 32 + 16) * 32];

    floatx4 acc[2][4];
#pragma unroll
    for (int i = 0; i < 2; i++)
#pragma unroll
        for (int j = 0; j < 4; j++) acc[i][j] = (floatx4){0.f, 0.f, 0.f, 0.f};

    const int wm = (wave >> 1) * 32, wn = (wave & 1) * 64;
    const int lr = lane & 15, lk = (lane >> 4) * 8;

    for (int k0 = 0; k0 < K; k0 += 32) {
        __syncthreads();
        gload16(gA0 + k0, lA0);
        gload16(gB0 + k0, lB0);
        gload16(gB1 + k0, lB1);
        __syncthreads();
        bhalf8 af[2], bfr[4];
#pragma unroll
        for (int i = 0; i < 2; i++)
            af[i] = *(const bhalf8*)&sA[(wm + i * 16 + lr) * 32 + lk];
#pragma unroll
        for (int i = 0; i < 4; i++)
            bfr[i] = *(const bhalf8*)&sB[(wn + i * 16 + lr) * 32 + lk];
#pragma unroll
        for (int mi = 0; mi < 2; mi++)
#pragma unroll
            for (int ni = 0; ni < 4; ni++)
                acc[mi][ni] = __builtin_amdgcn_mfma_f32_16x16x32_bf16(
                    af[mi], bfr[ni], acc[mi][ni], 0, 0, 0);
    }

    BF* Cb = C + (long)blockIdx.z * cStride;
#pragma unroll
    for (int ni = 0; ni < 4; ni++) {
        const int col = bn + wn + ni * 16 + lr;
#pragma unroll
        for (int mi = 0; mi < 2; mi++) {
            const int row0 = bm + wm + mi * 16 + (lane >> 4) * 4;
#pragma unroll
            for (int r = 0; r < 4; r++)
                Cb[(long)(row0 + r) * N + col] = __float2bfloat16(acc[mi][ni][r] * scale);
        }
    }
}

// ---------------------------------------------------------------------------
__global__ __launch_bounds__(256) void softmax4096(BF* __restrict__ S) {
    const long base = (long)blockIdx.x * 4096 + threadIdx.x * 16;
    const int tid = threadIdx.x, w = tid >> 6;
    bhalf8 u = *(bhalf8*)&S[base];
    bhalf8 u2 = *(bhalf8*)&S[base + 8];
    float v[16];
    float m = -1e30f;
#pragma unroll
    for (int j = 0; j < 8; j++) { v[j] = b2f(u[j]); v[8 + j] = b2f(u2[j]); }
#pragma unroll
    for (int j = 0; j < 16; j++) m = fmaxf(m, v[j]);
#pragma unroll
    for (int o = 32; o; o >>= 1) m = fmaxf(m, __shfl_xor(m, o));
    __shared__ float rm[4], rs[4];
    if ((tid & 63) == 0) rm[w] = m;
    __syncthreads();
    m = fmaxf(fmaxf(rm[0], rm[1]), fmaxf(rm[2], rm[3]));
    float s = 0.f;
#pragma unroll
    for (int j = 0; j < 16; j++) { v[j] = __expf(v[j] - m); s += v[j]; }
#pragma unroll
    for (int o = 32; o; o >>= 1) s += __shfl_xor(s, o);
    if ((tid & 63) == 0) rs[w] = s;
    __syncthreads();
    s = rs[0] + rs[1] + rs[2] + rs[3];
    const float inv = 1.0f / s;
#pragma unroll
    for (int j = 0; j < 8; j++) { u[j] = f2b(v[j] * inv); u2[j] = f2b(v[8 + j] * inv); }
    *(bhalf8*)&S[base] = u;
    *(bhalf8*)&S[base + 8] = u2;
}

// ---------------------------------------------------------------------------
extern "C" void kernel_launch(void* const* d_in, const int* in_sizes, int n_in,
                              void* d_out, int out_size, void* d_ws, size_t ws_size,
                              hipStream_t stream) {
    const float* x     = (const float*)d_in[0];
    const float* gamma = (const float*)d_in[1];
    const float* beta  = (const float*)d_in[2];
    const float* Wq    = (const float*)d_in[3];
    const float* bq    = (const float*)d_in[4];
    const float* Wk    = (const float*)d_in[5];
    const float* bk    = (const float*)d_in[6];
    const float* Wv    = (const float*)d_in[7];
    const float* bv    = (const float*)d_in[8];
    const float* Wo    = (const float*)d_in[9];
    float* out = (float*)d_out;

    const long ACTB = (long)NHW * NC;
    const long SB   = (long)NHW * NHW;
    const long WSZ  = (long)NC * NC;

    char* ws = (char*)d_ws;
    float* stats = (float*)ws;
    BF* wb = (BF*)(ws + 4096);
    BF* q  = wb + 4 * WSZ;
    BF* kk = q + NB * ACTB;
    BF* vT = kk + NB * ACTB;
    BF* R  = vT + NB * ACTB;
    BF* n = R;   // live: GN -> QKV GEMMs
    BF* S = R;   // live: attention chunks

    const size_t base_need = 4096ull + (size_t)4 * WSZ * 2 + (size_t)3 * NB * ACTB * 2;
    long sroom = (ws_size > base_need) ? (long)((ws_size - base_need) / (SB * 2)) : 1;
    int chunk = (int)(sroom < 1 ? 1 : (sroom > NB ? NB : sroom));
    while (NB % chunk) chunk--;              // 8,4,2,1

    f2b_convert4<<<1024, 256, 0, stream>>>(Wq, Wk, Wv, Wo, wb);

    gn_stats<<<NB * NG, 256, 0, stream>>>(x, stats);
    gn_apply<<<dim3(NHW / 64, NC / 64, NB), 256, 0, stream>>>(x, gamma, beta, stats, n);

    gemm256<true, false, false><<<dim3(NC / 256, NHW / 256, NB), 512, 0, stream>>>(
        n, ACTB, wb + 0 * WSZ, 0, q, ACTB, bq, nullptr, nullptr, NHW, NC, NC, 1.0f);
    gemm256<true, false, false><<<dim3(NC / 256, NHW / 256, NB), 512, 0, stream>>>(
        n, ACTB, wb + 1 * WSZ, 0, kk, ACTB, bk, nullptr, nullptr, NHW, NC, NC, 1.0f);
    gemm256<true, true, false><<<dim3(NC / 256, NHW / 256, NB), 512, 0, stream>>>(
        n, ACTB, wb + 2 * WSZ, 0, vT, ACTB, bv, nullptr, nullptr, NHW, NC, NC, 1.0f);

    const float iscl = 0.044194173824159216f;  // 1/sqrt(512)
    for (int b0 = 0; b0 < NB; b0 += chunk) {
        gemm256<false, false, false><<<dim3(NHW / 256, NHW / 256, chunk), 512, 0, stream>>>(
            q + b0 * ACTB, ACTB, kk + b0 * ACTB, ACTB, S, SB, nullptr, nullptr, nullptr,
            NHW, NHW, NC, iscl);
        softmax4096<<<NHW * chunk, 256, 0, stream>>>(S);
        if (chunk >= 4)
            gemm256<false, false, false><<<dim3(NC / 256, NHW / 256, chunk), 512, 0, stream>>>(
                S, SB, vT + b0 * ACTB, ACTB, q + b0 * ACTB, ACTB, nullptr, nullptr, nullptr,
                NHW, NC, NHW, 1.0f);
        else if (chunk == 2)
            gemm128<false, false><<<dim3(NC / 128, NHW / 128, chunk), 256, 0, stream>>>(
                S, SB, vT + b0 * ACTB, ACTB, q + b0 * ACTB, ACTB, nullptr, NHW, NC, NHW, 1.0f);
        else
            gemm64<<<dim3(NC / 128, NHW / 64, chunk), 256, 0, stream>>>(
                S, SB, vT + b0 * ACTB, ACTB, q + b0 * ACTB, ACTB, NC, NHW, 1.0f);
    }

    // final projection fused with transpose + residual add (writes f32 output)
    gemm256<false, true, true><<<dim3(NC / 256, NHW / 256, NB), 512, 0, stream>>>(
        q, ACTB, wb + 3 * WSZ, 0, nullptr, ACTB, nullptr, x, out, NHW, NC, NC, 1.0f);
}

// Round 3
// 790.886 us; speedup vs baseline: 1.0432x; 1.0432x over previous
//
#include <hip/hip_runtime.h>
#include <hip/hip_bf16.h>
#include <cstdint>
#include <cstddef>

typedef __hip_bfloat16 BF;
typedef __attribute__((ext_vector_type(8))) short bhalf8;   // 8 bf16 (MFMA A/B frag)
typedef __attribute__((ext_vector_type(4))) float floatx4;  // MFMA C/D frag

#define NB 8
#define NC 512
#define NHW 4096
#define NG 32

__device__ __forceinline__ float b2f(short h) {
    union { unsigned u; float f; } c;
    c.u = ((unsigned)(unsigned short)h) << 16;
    return c.f;
}
__device__ __forceinline__ short f2b(float f) {
    __hip_bfloat16 h = __float2bfloat16(f);
    short s;
    __builtin_memcpy(&s, &h, 2);
    return s;
}

// 16B global -> LDS direct (wave-uniform LDS base + lane*16)
__device__ __forceinline__ void gload16(const BF* g, BF* l) {
    __builtin_amdgcn_global_load_lds(
        (const __attribute__((address_space(1))) void*)g,
        (__attribute__((address_space(3))) void*)l, 16, 0, 0);
}

__device__ __forceinline__ void BARRIER() {
    asm volatile("" ::: "memory");
    __builtin_amdgcn_s_barrier();
    asm volatile("" ::: "memory");
}
#define WAITVM(N) asm volatile("s_waitcnt vmcnt(" #N ")" ::: "memory")
#define WAITLGKM() asm volatile("s_waitcnt lgkmcnt(0)" ::: "memory")

// T1: bijective XCD-aware tile swizzle (nwg % 8 == 0 for all our grids)
__device__ __forceinline__ void xcd_swizzle(int& bx, int& by) {
    const int gx = gridDim.x;
    const int nwg = gx * gridDim.y;
    if ((nwg & 7) == 0) {
        const int lin = by * gx + bx;
        const int cpx = nwg >> 3;
        const int s = (lin & 7) * cpx + (lin >> 3);
        bx = s % gx;
        by = s / gx;
    }
}

// ---------------------------------------------------------------------------
__global__ __launch_bounds__(256) void f2b_convert4(const float* __restrict__ s0,
                                                    const float* __restrict__ s1,
                                                    const float* __restrict__ s2,
                                                    const float* __restrict__ s3,
                                                    BF* __restrict__ dst) {
    const int which = blockIdx.x >> 8;
    const float* src = (which == 0) ? s0 : (which == 1) ? s1 : (which == 2) ? s2 : s3;
    BF* d = dst + (long)which * (NC * NC);
    const int i = ((blockIdx.x & 255) * 256 + threadIdx.x) * 4;
    float4 v = *(const float4*)&src[i];
    d[i]     = __float2bfloat16(v.x);
    d[i + 1] = __float2bfloat16(v.y);
    d[i + 2] = __float2bfloat16(v.z);
    d[i + 3] = __float2bfloat16(v.w);
}

// ---------------------------------------------------------------------------
__global__ __launch_bounds__(256) void gn_stats(const float* __restrict__ x,
                                                float* __restrict__ stats) {
    const int bg = blockIdx.x;
    const long base = (long)bg * 65536;
    float s = 0.f, q = 0.f;
    for (int i = threadIdx.x * 4; i < 65536; i += 256 * 4) {
        float4 v4 = *(const float4*)&x[base + i];
        s += v4.x + v4.y + v4.z + v4.w;
        q += v4.x * v4.x + v4.y * v4.y + v4.z * v4.z + v4.w * v4.w;
    }
#pragma unroll
    for (int o = 32; o; o >>= 1) { s += __shfl_down(s, o); q += __shfl_down(q, o); }
    __shared__ float rs[4], rq[4];
    const int w = threadIdx.x >> 6;
    if ((threadIdx.x & 63) == 0) { rs[w] = s; rq[w] = q; }
    __syncthreads();
    if (threadIdx.x == 0) {
        s = rs[0] + rs[1] + rs[2] + rs[3];
        q = rq[0] + rq[1] + rq[2] + rq[3];
        float mean = s * (1.f / 65536.f);
        float var = q * (1.f / 65536.f) - mean * mean;
        stats[2 * bg]     = mean;
        stats[2 * bg + 1] = rsqrtf(fmaxf(var, 0.f) + 1e-6f);
    }
}

// ---------------------------------------------------------------------------
__global__ __launch_bounds__(256) void gn_apply(const float* __restrict__ x,
                                                const float* __restrict__ gamma,
                                                const float* __restrict__ beta,
                                                const float* __restrict__ stats,
                                                BF* __restrict__ n) {
    __shared__ float tile[64][65];
    const int b = blockIdx.z, c0 = blockIdx.y * 64, s0 = blockIdx.x * 64;
    const long xbase = ((long)b * NC + c0) * NHW + s0;
#pragma unroll
    for (int i = 0; i < 16; i++) {
        int lin = i * 256 + threadIdx.x;
        int cl = lin >> 6, sl = lin & 63;
        int c = c0 + cl;
        float2 mr = ((const float2*)stats)[b * NG + (c >> 4)];
        float v = x[xbase + (long)cl * NHW + sl];
        v = (v - mr.x) * mr.y * gamma[c] + beta[c];
        tile[cl][sl] = v;
    }
    __syncthreads();
    const long nbase = ((long)b * NHW + s0) * NC + c0;
#pragma unroll
    for (int i = 0; i < 16; i++) {
        int lin = i * 256 + threadIdx.x;
        int sl = lin >> 6, cl = lin & 63;
        n[nbase + (long)sl * NC + cl] = __float2bfloat16(tile[cl][sl]);
    }
}

// ---------------------------------------------------------------------------
// 256x256 8-phase GEMM (T1+T2+T3+T4+T5). C[m][n] = scale*sum_k A[m][k]*B[n][k]
// (+bias[n]). A [M,K] lda, B [N,K] ldb, K-contig bf16. BK=64, 8 waves (2Mx4N),
// each 128x64 out. LDS 128KB: 2 dbuf x {A0,A1,B0,B1} 16KB regions.
// T2 swizzle: byte ^= ((row&7)<<4) within each region (row = byte>>7, 128B rows)
// -> rows 0..7 spread over 8 distinct 16B slots -> 2 lanes/bank (free, m136).
// Applied as: linear LDS dest + inverse-swizzled GLOBAL source (staging) +
// swizzled ds_read offsets (reads). Counted vmcnt(6) at phases 4/8 keeps 3
// half-tiles in flight across barriers.
// SPLITK: z = 2*bz+kh; A += kh*K, B += kh*K; writes f32 partial to outF+z*cStride.
// ---------------------------------------------------------------------------
#define LDA8(buf, mf, ks) (*(const bhalf8*)(sL + (buf) * 65536 + ((ks) ? aOff1 : aOff0) + (mf) * 2048))
#define LDB8(buf, nf, ks) (*(const bhalf8*)(sL + (buf) * 65536 + ((ks) ? bOff1 : bOff0) + (nf) * 2048))
#define QUAD(M0, N0)                                                                     \
    {                                                                                    \
        _Pragma("unroll") for (int mf = (M0); mf < (M0) + 4; mf++)                       \
            _Pragma("unroll") for (int nf = (N0); nf < (N0) + 2; nf++) {                 \
            acc[mf][nf] = __builtin_amdgcn_mfma_f32_16x16x32_bf16(                       \
                aR[mf & 3][0], bR[nf][0], acc[mf][nf], 0, 0, 0);                         \
            acc[mf][nf] = __builtin_amdgcn_mfma_f32_16x16x32_bf16(                       \
                aR[mf & 3][1], bR[nf][1], acc[mf][nf], 0, 0, 0);                         \
        }                                                                                \
    }

template <bool BIAS, bool TRANS, bool RESID, bool SPLITK>
__global__ __launch_bounds__(512) void gemm256(
    const BF* __restrict__ A, long aStride,
    const BF* __restrict__ Bm, long bStride,
    BF* __restrict__ C, long cStride,
    const float* __restrict__ bias,
    const float* __restrict__ resid, float* __restrict__ outF,
    int M, int N, int K, float scale, long lda, long ldb)
{
    __shared__ __align__(16) char sL[131072];
    const int tid = threadIdx.x;
    const int wave = tid >> 6, lane = tid & 63;
    int bxi = blockIdx.x, byi = blockIdx.y;
    xcd_swizzle(bxi, byi);
    const int bm = byi * 256, bn = bxi * 256;
    const int zz = blockIdx.z;
    const int bz = SPLITK ? (zz >> 1) : zz;
    const int kh = SPLITK ? (zz & 1) : 0;
    const BF* Ab = A + (long)bz * aStride + (long)kh * K + (long)bm * lda;
    const BF* Bb = Bm + (long)bz * bStride + (long)kh * K + (long)bn * ldb;

    // staging: LDS dest linear (tid*16 within half-region pair); global source
    // carries the inverse swizzle (same involution: bits4-6 ^= row&7)
    const int d0 = tid * 16, d1 = 8192 + tid * 16;
    const int r0 = d0 >> 7, r1 = d1 >> 7;
    const int c0s = ((d0 ^ ((r0 & 7) << 4)) & 127) >> 1;
    const int c1s = ((d1 ^ ((r1 & 7) << 4)) & 127) >> 1;
    const long sA0 = (long)r0 * lda + c0s, sA1 = (long)r1 * lda + c1s;
    const long sB0 = (long)r0 * ldb + c0s, sB1 = (long)r1 * ldb + c1s;
    const int lds0 = wave * 1024;           // wave-uniform; HW adds lane*16
    const int lds1 = 8192 + wave * 1024;

    // frag ds_read offsets with the same swizzle (lane-constant fold)
    const int lr = lane & 15, lk2 = (lane >> 4) * 16;
    const int swz = (lr & 7) << 4;
    const int sb0 = lr * 128 + (lk2 ^ swz);          // ks=0
    const int sb1 = lr * 128 + ((lk2 + 64) ^ swz);   // ks=1
    const int aReg = (wave >> 2) * 16384;
    const int bReg = (2 + ((wave >> 1) & 1)) * 16384 + (wave & 1) * 8192;
    const int aOff0 = aReg + sb0, aOff1 = aReg + sb1;
    const int bOff0 = bReg + sb0, bOff1 = bReg + sb1;

    auto STAGE = [&](int t, int region, int dbuf) {
        const bool isA = region < 2;
        const long ld = isA ? lda : ldb;
        const BF* g = (isA ? (Ab + (long)region * 128 * ld)
                           : (Bb + (long)(region - 2) * 128 * ld)) + (long)t * 64;
        char* lb = sL + dbuf * 65536 + region * 16384;
        gload16(g + (isA ? sA0 : sB0), (BF*)(lb + lds0));
        gload16(g + (isA ? sA1 : sB1), (BF*)(lb + lds1));
    };

    floatx4 acc[8][4];
#pragma unroll
    for (int i = 0; i < 8; i++)
#pragma unroll
        for (int j = 0; j < 4; j++) acc[i][j] = (floatx4){0.f, 0.f, 0.f, 0.f};

    const int nt = K >> 6, ngrp = nt >> 1;

    // prologue: T0 full + T1.{B0,B1,A0}; vmcnt(6) forces all 8 T0 loads done
    STAGE(0, 0, 0); STAGE(0, 1, 0); STAGE(0, 2, 0); STAGE(0, 3, 0);
    WAITVM(4);
    STAGE(1, 2, 1); STAGE(1, 3, 1); STAGE(1, 0, 1);
    WAITVM(6);
    BARRIER();

    bhalf8 aR[4][2], bR[4][2];

    for (int g = 0; g < ngrp; ++g) {
        const bool st = (g < ngrp - 1);
        const int t2 = 2 * g + 2, t3 = 2 * g + 3;

        // ---- phase 1 (tile 2g, buf0): A mf0-3, B nf0-1 (+nf2-3 for B0 waves)
#pragma unroll
        for (int mf = 0; mf < 4; mf++) { aR[mf][0] = LDA8(0, mf, 0); aR[mf][1] = LDA8(0, mf, 1); }
#pragma unroll
        for (int nf = 0; nf < 2; nf++) { bR[nf][0] = LDB8(0, nf, 0); bR[nf][1] = LDB8(0, nf, 1); }
        if (!(wave & 2)) {
#pragma unroll
            for (int nf = 2; nf < 4; nf++) { bR[nf][0] = LDB8(0, nf, 0); bR[nf][1] = LDB8(0, nf, 1); }
        }
        STAGE(2 * g + 1, 1, 1);          // T(2g+1).A1 -> buf1
        BARRIER(); WAITLGKM();
        __builtin_amdgcn_s_setprio(1);
        QUAD(0, 0);
        __builtin_amdgcn_s_setprio(0);
        BARRIER();

        // ---- phase 2: B1-waves read nf2-3; stage T2.B0 (buf0.B0 last read ph1)
        if (wave & 2) {
#pragma unroll
            for (int nf = 2; nf < 4; nf++) { bR[nf][0] = LDB8(0, nf, 0); bR[nf][1] = LDB8(0, nf, 1); }
        }
        if (st) STAGE(t2, 2, 0);
        BARRIER(); WAITLGKM();
        __builtin_amdgcn_s_setprio(1);
        QUAD(0, 2);
        __builtin_amdgcn_s_setprio(0);
        BARRIER();

        // ---- phase 3: A mf4-7; stage T2.B1 (buf0.B1 last read ph2)
#pragma unroll
        for (int mf = 4; mf < 8; mf++) { aR[mf & 3][0] = LDA8(0, mf, 0); aR[mf & 3][1] = LDA8(0, mf, 1); }
        if (st) STAGE(t2, 3, 0);
        BARRIER(); WAITLGKM();
        __builtin_amdgcn_s_setprio(1);
        QUAD(4, 0);
        __builtin_amdgcn_s_setprio(0);
        BARRIER();

        // ---- phase 4: stage T2.A0 (buf0.A0 last read ph3); boundary vmcnt
        if (st) STAGE(t2, 0, 0);
        BARRIER();
        __builtin_amdgcn_s_setprio(1);
        QUAD(4, 2);
        __builtin_amdgcn_s_setprio(0);
        if (st) { WAITVM(6); } else { WAITVM(0); }
        BARRIER();

        // ---- phase 5 (tile 2g+1, buf1): stage T2.A1 (buf0.A1 last read ph3)
#pragma unroll
        for (int mf = 0; mf < 4; mf++) { aR[mf][0] = LDA8(1, mf, 0); aR[mf][1] = LDA8(1, mf, 1); }
#pragma unroll
        for (int nf = 0; nf < 2; nf++) { bR[nf][0] = LDB8(1, nf, 0); bR[nf][1] = LDB8(1, nf, 1); }
        if (!(wave & 2)) {
#pragma unroll
            for (int nf = 2; nf < 4; nf++) { bR[nf][0] = LDB8(1, nf, 0); bR[nf][1] = LDB8(1, nf, 1); }
        }
        if (st) STAGE(t2, 1, 0);
        BARRIER(); WAITLGKM();
        __builtin_amdgcn_s_setprio(1);
        QUAD(0, 0);
        __builtin_amdgcn_s_setprio(0);
        BARRIER();

        // ---- phase 6: stage T3.B0 (buf1.B0 last read ph5)
        if (wave & 2) {
#pragma unroll
            for (int nf = 2; nf < 4; nf++) { bR[nf][0] = LDB8(1, nf, 0); bR[nf][1] = LDB8(1, nf, 1); }
        }
        if (st) STAGE(t3, 2, 1);
        BARRIER(); WAITLGKM();
        __builtin_amdgcn_s_setprio(1);
        QUAD(0, 2);
        __builtin_amdgcn_s_setprio(0);
        BARRIER();

        // ---- phase 7: stage T3.B1 (buf1.B1 last read ph6)
#pragma unroll
        for (int mf = 4; mf < 8; mf++) { aR[mf & 3][0] = LDA8(1, mf, 0); aR[mf & 3][1] = LDA8(1, mf, 1); }
        if (st) STAGE(t3, 3, 1);
        BARRIER(); WAITLGKM();
        __builtin_amdgcn_s_setprio(1);
        QUAD(4, 0);
        __builtin_amdgcn_s_setprio(0);
        BARRIER();

        // ---- phase 8: stage T3.A0 (buf1.A0 last read ph7); boundary vmcnt
        if (st) STAGE(t3, 0, 1);
        BARRIER();
        __builtin_amdgcn_s_setprio(1);
        QUAD(4, 2);
        __builtin_amdgcn_s_setprio(0);
        if (st) { WAITVM(6); }
        BARRIER();
    }

    // ---- epilogue
    const int wm = (wave >> 2) * 128, wn = (wave & 3) * 64;
    if (SPLITK) {
        float* Ob = outF + (long)zz * cStride;   // [bz][kh] partial layout
#pragma unroll
        for (int nf = 0; nf < 4; nf++) {
            const int col = bn + wn + nf * 16 + lr;
#pragma unroll
            for (int mf = 0; mf < 8; mf++) {
                const int row0 = bm + wm + mf * 16 + (lane >> 4) * 4;
#pragma unroll
                for (int r = 0; r < 4; r++)
                    Ob[(long)(row0 + r) * N + col] = acc[mf][nf][r] * scale;
            }
        }
        return;
    }
    if (RESID) {
        float* Ob = outF + (long)zz * cStride;
        const float* Xb = resid + (long)zz * cStride;
#pragma unroll
        for (int nf = 0; nf < 4; nf++) {
            const int col = bn + wn + nf * 16 + lr;
#pragma unroll
            for (int mf = 0; mf < 8; mf++) {
                const int row0 = bm + wm + mf * 16 + (lane >> 4) * 4;
                const long a = (long)col * M + row0;
                float4 xv = *(const float4*)&Xb[a];
                float4 ov;
                ov.x = acc[mf][nf][0] * scale + xv.x;
                ov.y = acc[mf][nf][1] * scale + xv.y;
                ov.z = acc[mf][nf][2] * scale + xv.z;
                ov.w = acc[mf][nf][3] * scale + xv.w;
                *(float4*)&Ob[a] = ov;
            }
        }
        return;
    }
    BF* Cb = C + (long)zz * cStride;
#pragma unroll
    for (int nf = 0; nf < 4; nf++) {
        const int col = bn + wn + nf * 16 + lr;
        const float bv = BIAS ? bias[col] : 0.0f;
#pragma unroll
        for (int mf = 0; mf < 8; mf++) {
            const int row0 = bm + wm + mf * 16 + (lane >> 4) * 4;
#pragma unroll
            for (int r = 0; r < 4; r++) {
                float v = acc[mf][nf][r] * scale + bv;
                if (TRANS) Cb[(long)col * M + row0 + r] = __float2bfloat16(v);
                else       Cb[(long)(row0 + r) * N + col] = __float2bfloat16(v);
            }
        }
    }
}

// ---------------------------------------------------------------------------
// split-K reduce: q[bz][e] = bf16(P[bz][0][e] + P[bz][1][e])
__global__ __launch_bounds__(256) void splitk_reduce(const float* __restrict__ P,
                                                     BF* __restrict__ dst,
                                                     long perBatch) {
    const long off = ((long)blockIdx.x * 256 + threadIdx.x) * 4;
    const float* p0 = P + (long)blockIdx.y * 2 * perBatch;
    float4 a = *(const float4*)&p0[off];
    float4 b = *(const float4*)&p0[perBatch + off];
    BF* d = dst + (long)blockIdx.y * perBatch + off;
    short4 o;
    o.x = f2b(a.x + b.x);
    o.y = f2b(a.y + b.y);
    o.z = f2b(a.z + b.z);
    o.w = f2b(a.w + b.w);
    *(short4*)d = o;
}

// ---------------------------------------------------------------------------
// GEMM 128x128 tile, BK=32 (m97-style) — fallback for PV at chunk==2.
// ---------------------------------------------------------------------------
template <bool BIAS, bool TRANS>
__global__ __launch_bounds__(256, 2) void gemm128(
    const BF* __restrict__ A, long aStride,
    const BF* __restrict__ Bm, long bStride,
    BF* __restrict__ C, long cStride,
    const float* __restrict__ bias,
    int M, int N, int K, float scale)
{
    __shared__ __align__(16) BF sA[128 * 32];
    __shared__ __align__(16) BF sB[128 * 32];
    const int tid = threadIdx.x;
    const int wave = tid >> 6, lane = tid & 63;
    int bxi = blockIdx.x, byi = blockIdx.y;
    xcd_swizzle(bxi, byi);
    const int bm = byi * 128, bn = bxi * 128;
    const BF* Ab = A + (long)blockIdx.z * aStride + (long)bm * K;
    const BF* Bb = Bm + (long)blockIdx.z * bStride + (long)bn * K;

    const int srow = wave * 32 + (lane >> 2);
    const int sk = (lane & 3) * 8;
    const BF* gA0 = Ab + (long)srow * K + sk;
    const BF* gA1 = gA0 + (long)16 * K;
    const BF* gB0 = Bb + (long)srow * K + sk;
    const BF* gB1 = gB0 + (long)16 * K;
    BF* lA0 = &sA[(wave * 32) * 32];
    BF* lA1 = &sA[(wave * 32 + 16) * 32];
    BF* lB0 = &sB[(wave * 32) * 32];
    BF* lB1 = &sB[(wave * 32 + 16) * 32];

    floatx4 acc[4][4];
#pragma unroll
    for (int i = 0; i < 4; i++)
#pragma unroll
        for (int j = 0; j < 4; j++) acc[i][j] = (floatx4){0.f, 0.f, 0.f, 0.f};

    const int wm = (wave >> 1) * 64, wn = (wave & 1) * 64;
    const int lr = lane & 15, lk = (lane >> 4) * 8;

    for (int k0 = 0; k0 < K; k0 += 32) {
        __syncthreads();
        gload16(gA0 + k0, lA0);
        gload16(gA1 + k0, lA1);
        gload16(gB0 + k0, lB0);
        gload16(gB1 + k0, lB1);
        __syncthreads();
        bhalf8 af[4], bfr[4];
#pragma unroll
        for (int i = 0; i < 4; i++)
            af[i] = *(const bhalf8*)&sA[(wm + i * 16 + lr) * 32 + lk];
#pragma unroll
        for (int i = 0; i < 4; i++)
            bfr[i] = *(const bhalf8*)&sB[(wn + i * 16 + lr) * 32 + lk];
#pragma unroll
        for (int mi = 0; mi < 4; mi++)
#pragma unroll
            for (int ni = 0; ni < 4; ni++)
                acc[mi][ni] = __builtin_amdgcn_mfma_f32_16x16x32_bf16(
                    af[mi], bfr[ni], acc[mi][ni], 0, 0, 0);
    }

    BF* Cb = C + (long)blockIdx.z * cStride;
#pragma unroll
    for (int ni = 0; ni < 4; ni++) {
        const int col = bn + wn + ni * 16 + lr;
        const float bv = BIAS ? bias[col] : 0.0f;
#pragma unroll
        for (int mi = 0; mi < 4; mi++) {
            const int row0 = bm + wm + mi * 16 + (lane >> 4) * 4;
#pragma unroll
            for (int r = 0; r < 4; r++) {
                float v = acc[mi][ni][r] * scale + bv;
                if (TRANS) Cb[(long)col * M + row0 + r] = __float2bfloat16(v);
                else       Cb[(long)(row0 + r) * N + col] = __float2bfloat16(v);
            }
        }
    }
}

// ---------------------------------------------------------------------------
// GEMM 64(M)x128(N) tile — fallback for PV at chunk==1.
// ---------------------------------------------------------------------------
__global__ __launch_bounds__(256, 2) void gemm64(
    const BF* __restrict__ A, long aStride,
    const BF* __restrict__ Bm, long bStride,
    BF* __restrict__ C, long cStride,
    int N, int K, float scale)
{
    __shared__ __align__(16) BF sA[64 * 32];
    __shared__ __align__(16) BF sB[128 * 32];
    const int tid = threadIdx.x;
    const int wave = tid >> 6, lane = tid & 63;
    int bxi = blockIdx.x, byi = blockIdx.y;
    xcd_swizzle(bxi, byi);
    const int bm = byi * 64, bn = bxi * 128;
    const BF* Ab = A + (long)blockIdx.z * aStride + (long)bm * K;
    const BF* Bb = Bm + (long)blockIdx.z * bStride + (long)bn * K;

    const int rowoff = lane >> 2, sk = (lane & 3) * 8;
    const BF* gA0 = Ab + (long)(wave * 16 + rowoff) * K + sk;
    const BF* gB0 = Bb + (long)(wave * 32 + rowoff) * K + sk;
    const BF* gB1 = gB0 + (long)16 * K;
    BF* lA0 = &sA[(wave * 16) * 32];
    BF* lB0 = &sB[(wave * 32) * 32];
    BF* lB1 = &sB[(wave * 32 + 16) * 32];

    floatx4 acc[2][4];
#pragma unroll
    for (int i = 0; i < 2; i++)
#pragma unroll
        for (int j = 0; j < 4; j++) acc[i][j] = (floatx4){0.f, 0.f, 0.f, 0.f};

    const int wm = (wave >> 1) * 32, wn = (wave & 1) * 64;
    const int lr = lane & 15, lk = (lane >> 4) * 8;

    for (int k0 = 0; k0 < K; k0 += 32) {
        __syncthreads();
        gload16(gA0 + k0, lA0);
        gload16(gB0 + k0, lB0);
        gload16(gB1 + k0, lB1);
        __syncthreads();
        bhalf8 af[2], bfr[4];
#pragma unroll
        for (int i = 0; i < 2; i++)
            af[i] = *(const bhalf8*)&sA[(wm + i * 16 + lr) * 32 + lk];
#pragma unroll
        for (int i = 0; i < 4; i++)
            bfr[i] = *(const bhalf8*)&sB[(wn + i * 16 + lr) * 32 + lk];
#pragma unroll
        for (int mi = 0; mi < 2; mi++)
#pragma unroll
            for (int ni = 0; ni < 4; ni++)
                acc[mi][ni] = __builtin_amdgcn_mfma_f32_16x16x32_bf16(
                    af[mi], bfr[ni], acc[mi][ni], 0, 0, 0);
    }

    BF* Cb = C + (long)blockIdx.z * cStride;
#pragma unroll
    for (int ni = 0; ni < 4; ni++) {
        const int col = bn + wn + ni * 16 + lr;
#pragma unroll
        for (int mi = 0; mi < 2; mi++) {
            const int row0 = bm + wm + mi * 16 + (lane >> 4) * 4;
#pragma unroll
            for (int r = 0; r < 4; r++)
                Cb[(long)(row0 + r) * N + col] = __float2bfloat16(acc[mi][ni][r] * scale);
        }
    }
}

// ---------------------------------------------------------------------------
__global__ __launch_bounds__(256) void softmax4096(BF* __restrict__ S) {
    const long base = (long)blockIdx.x * 4096 + threadIdx.x * 16;
    const int tid = threadIdx.x, w = tid >> 6;
    bhalf8 u = *(bhalf8*)&S[base];
    bhalf8 u2 = *(bhalf8*)&S[base + 8];
    float v[16];
    float m = -1e30f;
#pragma unroll
    for (int j = 0; j < 8; j++) { v[j] = b2f(u[j]); v[8 + j] = b2f(u2[j]); }
#pragma unroll
    for (int j = 0; j < 16; j++) m = fmaxf(m, v[j]);
#pragma unroll
    for (int o = 32; o; o >>= 1) m = fmaxf(m, __shfl_xor(m, o));
    __shared__ float rm[4], rs[4];
    if ((tid & 63) == 0) rm[w] = m;
    __syncthreads();
    m = fmaxf(fmaxf(rm[0], rm[1]), fmaxf(rm[2], rm[3]));
    float s = 0.f;
#pragma unroll
    for (int j = 0; j < 16; j++) { v[j] = __expf(v[j] - m); s += v[j]; }
#pragma unroll
    for (int o = 32; o; o >>= 1) s += __shfl_xor(s, o);
    if ((tid & 63) == 0) rs[w] = s;
    __syncthreads();
    s = rs[0] + rs[1] + rs[2] + rs[3];
    const float inv = 1.0f / s;
#pragma unroll
    for (int j = 0; j < 8; j++) { u[j] = f2b(v[j] * inv); u2[j] = f2b(v[8 + j] * inv); }
    *(bhalf8*)&S[base] = u;
    *(bhalf8*)&S[base + 8] = u2;
}

// ---------------------------------------------------------------------------
extern "C" void kernel_launch(void* const* d_in, const int* in_sizes, int n_in,
                              void* d_out, int out_size, void* d_ws, size_t ws_size,
                              hipStream_t stream) {
    const float* x     = (const float*)d_in[0];
    const float* gamma = (const float*)d_in[1];
    const float* beta  = (const float*)d_in[2];
    const float* Wq    = (const float*)d_in[3];
    const float* bq    = (const float*)d_in[4];
    const float* Wk    = (const float*)d_in[5];
    const float* bk    = (const float*)d_in[6];
    const float* Wv    = (const float*)d_in[7];
    const float* bv    = (const float*)d_in[8];
    const float* Wo    = (const float*)d_in[9];
    float* out = (float*)d_out;

    const long ACTB = (long)NHW * NC;
    const long SB   = (long)NHW * NHW;
    const long WSZ  = (long)NC * NC;

    char* ws = (char*)d_ws;
    float* stats = (float*)ws;
    BF* wb = (BF*)(ws + 4096);
    BF* q  = wb + 4 * WSZ;
    BF* kk = q + NB * ACTB;
    BF* vT = kk + NB * ACTB;
    BF* R  = vT + NB * ACTB;
    BF* n = R;   // live: GN -> QKV GEMMs
    BF* S = R;   // live: attention chunks

    const size_t base_need = 4096ull + (size_t)4 * WSZ * 2 + (size_t)3 * NB * ACTB * 2;
    long sroom = (ws_size > base_need) ? (long)((ws_size - base_need) / (SB * 2)) : 1;
    int chunk = (int)(sroom < 1 ? 1 : (sroom > NB ? NB : sroom));
    while (NB % chunk) chunk--;              // 8,4,2,1

    // split-K PV partials (f32, [bz][kh][ACTB]) after S, if room
    float* Pf = (float*)(R + (long)chunk * SB);
    const size_t splitNeed = base_need + (size_t)chunk * SB * 2
                           + (size_t)chunk * 2 * ACTB * 4;
    const bool doSplit = (chunk >= 2) && (ws_size >= splitNeed);

    f2b_convert4<<<1024, 256, 0, stream>>>(Wq, Wk, Wv, Wo, wb);

    gn_stats<<<NB * NG, 256, 0, stream>>>(x, stats);
    gn_apply<<<dim3(NHW / 64, NC / 64, NB), 256, 0, stream>>>(x, gamma, beta, stats, n);

    gemm256<true, false, false, false><<<dim3(NC / 256, NHW / 256, NB), 512, 0, stream>>>(
        n, ACTB, wb + 0 * WSZ, 0, q, ACTB, bq, nullptr, nullptr, NHW, NC, NC, 1.0f, NC, NC);
    gemm256<true, false, false, false><<<dim3(NC / 256, NHW / 256, NB), 512, 0, stream>>>(
        n, ACTB, wb + 1 * WSZ, 0, kk, ACTB, bk, nullptr, nullptr, NHW, NC, NC, 1.0f, NC, NC);
    gemm256<true, true, false, false><<<dim3(NC / 256, NHW / 256, NB), 512, 0, stream>>>(
        n, ACTB, wb + 2 * WSZ, 0, vT, ACTB, bv, nullptr, nullptr, NHW, NC, NC, 1.0f, NC, NC);

    const float iscl = 0.044194173824159216f;  // 1/sqrt(512)
    for (int b0 = 0; b0 < NB; b0 += chunk) {
        gemm256<false, false, false, false><<<dim3(NHW / 256, NHW / 256, chunk), 512, 0, stream>>>(
            q + b0 * ACTB, ACTB, kk + b0 * ACTB, ACTB, S, SB, nullptr, nullptr, nullptr,
            NHW, NHW, NC, iscl, NC, NC);
        softmax4096<<<NHW * chunk, 256, 0, stream>>>(S);
        if (doSplit) {
            // PV split-K=2: z = 2*bz+kh, each half K=2048; f32 partials, then reduce
            gemm256<false, false, false, true><<<dim3(NC / 256, NHW / 256, chunk * 2), 512, 0, stream>>>(
                S, SB, vT + b0 * ACTB, ACTB, nullptr, ACTB, nullptr, nullptr, Pf,
                NHW, NC, NHW / 2, 1.0f, NHW, NHW);
            splitk_reduce<<<dim3((unsigned)(ACTB / 1024), chunk), 256, 0, stream>>>(
                Pf, q + b0 * ACTB, ACTB);
        } else if (chunk >= 4) {
            gemm256<false, false, false, false><<<dim3(NC / 256, NHW / 256, chunk), 512, 0, stream>>>(
                S, SB, vT + b0 * ACTB, ACTB, q + b0 * ACTB, ACTB, nullptr, nullptr, nullptr,
                NHW, NC, NHW, 1.0f, NHW, NHW);
        } else if (chunk == 2) {
            gemm128<false, false><<<dim3(NC / 128, NHW / 128, chunk), 256, 0, stream>>>(
                S, SB, vT + b0 * ACTB, ACTB, q + b0 * ACTB, ACTB, nullptr, NHW, NC, NHW, 1.0f);
        } else {
            gemm64<<<dim3(NC / 128, NHW / 64, chunk), 256, 0, stream>>>(
                S, SB, vT + b0 * ACTB, ACTB, q + b0 * ACTB, ACTB, NC, NHW, 1.0f);
        }
    }

    // final projection fused with transpose + residual add (writes f32 output)
    gemm256<false, true, true, false><<<dim3(NC / 256, NHW / 256, NB), 512, 0, stream>>>(
        q, ACTB, wb + 3 * WSZ, 0, nullptr, ACTB, nullptr, x, out, NHW, NC, NC, 1.0f, NC, NC);
}

// Round 4
// 785.479 us; speedup vs baseline: 1.0504x; 1.0069x over previous
//
#include <hip/hip_runtime.h>
#include <hip/hip_bf16.h>
#include <cstdint>
#include <cstddef>

typedef __hip_bfloat16 BF;
typedef __attribute__((ext_vector_type(8))) short bhalf8;   // 8 bf16 (MFMA A/B frag)
typedef __attribute__((ext_vector_type(4))) float floatx4;  // MFMA C/D frag

#define NB 8
#define NC 512
#define NHW 4096
#define NG 32

__device__ __forceinline__ float b2f(short h) {
    union { unsigned u; float f; } c;
    c.u = ((unsigned)(unsigned short)h) << 16;
    return c.f;
}
__device__ __forceinline__ short f2b(float f) {
    __hip_bfloat16 h = __float2bfloat16(f);
    short s;
    __builtin_memcpy(&s, &h, 2);
    return s;
}

// 16B global -> LDS direct (wave-uniform LDS base + lane*16)
__device__ __forceinline__ void gload16(const BF* g, BF* l) {
    __builtin_amdgcn_global_load_lds(
        (const __attribute__((address_space(1))) void*)g,
        (__attribute__((address_space(3))) void*)l, 16, 0, 0);
}

__device__ __forceinline__ void BARRIER() {
    asm volatile("" ::: "memory");
    __builtin_amdgcn_s_barrier();
    asm volatile("" ::: "memory");
}
#define WAITVM(N) asm volatile("s_waitcnt vmcnt(" #N ")" ::: "memory")
#define WAITLGKM() asm volatile("s_waitcnt lgkmcnt(0)" ::: "memory")

// T1: bijective XCD-aware tile swizzle (nwg % 8 == 0 for all our grids)
__device__ __forceinline__ void xcd_swizzle(int& bx, int& by) {
    const int gx = gridDim.x;
    const int nwg = gx * gridDim.y;
    if ((nwg & 7) == 0) {
        const int lin = by * gx + bx;
        const int cpx = nwg >> 3;
        const int s = (lin & 7) * cpx + (lin >> 3);
        bx = s % gx;
        by = s / gx;
    }
}

// ---------------------------------------------------------------------------
__global__ __launch_bounds__(256) void f2b_convert4(const float* __restrict__ s0,
                                                    const float* __restrict__ s1,
                                                    const float* __restrict__ s2,
                                                    const float* __restrict__ s3,
                                                    BF* __restrict__ dst) {
    const int which = blockIdx.x >> 8;
    const float* src = (which == 0) ? s0 : (which == 1) ? s1 : (which == 2) ? s2 : s3;
    BF* d = dst + (long)which * (NC * NC);
    const int i = ((blockIdx.x & 255) * 256 + threadIdx.x) * 4;
    float4 v = *(const float4*)&src[i];
    d[i]     = __float2bfloat16(v.x);
    d[i + 1] = __float2bfloat16(v.y);
    d[i + 2] = __float2bfloat16(v.z);
    d[i + 3] = __float2bfloat16(v.w);
}

// ---------------------------------------------------------------------------
__global__ __launch_bounds__(256) void gn_stats(const float* __restrict__ x,
                                                float* __restrict__ stats) {
    const int bg = blockIdx.x;
    const long base = (long)bg * 65536;
    float s = 0.f, q = 0.f;
    for (int i = threadIdx.x * 4; i < 65536; i += 256 * 4) {
        float4 v4 = *(const float4*)&x[base + i];
        s += v4.x + v4.y + v4.z + v4.w;
        q += v4.x * v4.x + v4.y * v4.y + v4.z * v4.z + v4.w * v4.w;
    }
#pragma unroll
    for (int o = 32; o; o >>= 1) { s += __shfl_down(s, o); q += __shfl_down(q, o); }
    __shared__ float rs[4], rq[4];
    const int w = threadIdx.x >> 6;
    if ((threadIdx.x & 63) == 0) { rs[w] = s; rq[w] = q; }
    __syncthreads();
    if (threadIdx.x == 0) {
        s = rs[0] + rs[1] + rs[2] + rs[3];
        q = rq[0] + rq[1] + rq[2] + rq[3];
        float mean = s * (1.f / 65536.f);
        float var = q * (1.f / 65536.f) - mean * mean;
        stats[2 * bg]     = mean;
        stats[2 * bg + 1] = rsqrtf(fmaxf(var, 0.f) + 1e-6f);
    }
}

// ---------------------------------------------------------------------------
__global__ __launch_bounds__(256) void gn_apply(const float* __restrict__ x,
                                                const float* __restrict__ gamma,
                                                const float* __restrict__ beta,
                                                const float* __restrict__ stats,
                                                BF* __restrict__ n) {
    __shared__ float tile[64][65];
    const int b = blockIdx.z, c0 = blockIdx.y * 64, s0 = blockIdx.x * 64;
    const long xbase = ((long)b * NC + c0) * NHW + s0;
#pragma unroll
    for (int i = 0; i < 16; i++) {
        int lin = i * 256 + threadIdx.x;
        int cl = lin >> 6, sl = lin & 63;
        int c = c0 + cl;
        float2 mr = ((const float2*)stats)[b * NG + (c >> 4)];
        float v = x[xbase + (long)cl * NHW + sl];
        v = (v - mr.x) * mr.y * gamma[c] + beta[c];
        tile[cl][sl] = v;
    }
    __syncthreads();
    const long nbase = ((long)b * NHW + s0) * NC + c0;
#pragma unroll
    for (int i = 0; i < 16; i++) {
        int lin = i * 256 + threadIdx.x;
        int sl = lin >> 6, cl = lin & 63;
        n[nbase + (long)sl * NC + cl] = __float2bfloat16(tile[cl][sl]);
    }
}

// ---------------------------------------------------------------------------
// 256x256 8-phase GEMM (T1+T2+T3+T4+T5). C[m][n] = scale*sum_k A[m][k]*B[n][k]
// (+bias[n]). A [M,K] lda, B [N,K] ldb, K-contig bf16. BK=64, 8 waves (2Mx4N),
// each 128x64 out. LDS 128KB: 2 dbuf x {A0,A1,B0,B1} 16KB regions.
// T2 swizzle: byte ^= ((row&7)<<4) within each region -> SQ_LDS_BANK_CONFLICT=0
// (verified R3). Counted vmcnt(6) at phases 4/8 keeps 3 half-tiles in flight.
// QUAD is ks-OUTER: all 8 independent accumulators at ks=0 then ks=1 ->
// RAW distance 8 (was 1: back-to-back dependent MFMA pairs stalled the pipe).
// SPLITK: z = 2*bz+kh; A += kh*K, B += kh*K; writes f32 partial to outF+z*cStride.
// ---------------------------------------------------------------------------
#define LDA8(buf, mf, ks) (*(const bhalf8*)(sL + (buf) * 65536 + ((ks) ? aOff1 : aOff0) + (mf) * 2048))
#define LDB8(buf, nf, ks) (*(const bhalf8*)(sL + (buf) * 65536 + ((ks) ? bOff1 : bOff0) + (nf) * 2048))
#define QUAD(M0, N0)                                                                     \
    {                                                                                    \
        _Pragma("unroll") for (int ks = 0; ks < 2; ks++)                                 \
            _Pragma("unroll") for (int mf = (M0); mf < (M0) + 4; mf++)                   \
                _Pragma("unroll") for (int nf = (N0); nf < (N0) + 2; nf++)               \
                    acc[mf][nf] = __builtin_amdgcn_mfma_f32_16x16x32_bf16(               \
                        aR[mf & 3][ks], bR[nf][ks], acc[mf][nf], 0, 0, 0);               \
    }

template <bool BIAS, bool TRANS, bool RESID, bool SPLITK>
__global__ __launch_bounds__(512) void gemm256(
    const BF* __restrict__ A, long aStride,
    const BF* __restrict__ Bm, long bStride,
    BF* __restrict__ C, long cStride,
    const float* __restrict__ bias,
    const float* __restrict__ resid, float* __restrict__ outF,
    int M, int N, int K, float scale, long lda, long ldb)
{
    __shared__ __align__(16) char sL[131072];
    const int tid = threadIdx.x;
    const int wave = tid >> 6, lane = tid & 63;
    int bxi = blockIdx.x, byi = blockIdx.y;
    xcd_swizzle(bxi, byi);
    const int bm = byi * 256, bn = bxi * 256;
    const int zz = blockIdx.z;
    const int bz = SPLITK ? (zz >> 1) : zz;
    const int kh = SPLITK ? (zz & 1) : 0;
    const BF* Ab = A + (long)bz * aStride + (long)kh * K + (long)bm * lda;
    const BF* Bb = Bm + (long)bz * bStride + (long)kh * K + (long)bn * ldb;

    // staging: LDS dest linear; global source carries the inverse swizzle
    const int d0 = tid * 16, d1 = 8192 + tid * 16;
    const int r0 = d0 >> 7, r1 = d1 >> 7;
    const int c0s = ((d0 ^ ((r0 & 7) << 4)) & 127) >> 1;
    const int c1s = ((d1 ^ ((r1 & 7) << 4)) & 127) >> 1;
    const long sA0 = (long)r0 * lda + c0s, sA1 = (long)r1 * lda + c1s;
    const long sB0 = (long)r0 * ldb + c0s, sB1 = (long)r1 * ldb + c1s;
    const int lds0 = wave * 1024;           // wave-uniform; HW adds lane*16
    const int lds1 = 8192 + wave * 1024;

    // frag ds_read offsets with the same swizzle (lane-constant fold)
    const int lr = lane & 15, lk2 = (lane >> 4) * 16;
    const int swz = (lr & 7) << 4;
    const int sb0 = lr * 128 + (lk2 ^ swz);          // ks=0
    const int sb1 = lr * 128 + ((lk2 + 64) ^ swz);   // ks=1
    const int aReg = (wave >> 2) * 16384;
    const int bReg = (2 + ((wave >> 1) & 1)) * 16384 + (wave & 1) * 8192;
    const int aOff0 = aReg + sb0, aOff1 = aReg + sb1;
    const int bOff0 = bReg + sb0, bOff1 = bReg + sb1;

    auto STAGE = [&](int t, int region, int dbuf) {
        const bool isA = region < 2;
        const long ld = isA ? lda : ldb;
        const BF* g = (isA ? (Ab + (long)region * 128 * ld)
                           : (Bb + (long)(region - 2) * 128 * ld)) + (long)t * 64;
        char* lb = sL + dbuf * 65536 + region * 16384;
        gload16(g + (isA ? sA0 : sB0), (BF*)(lb + lds0));
        gload16(g + (isA ? sA1 : sB1), (BF*)(lb + lds1));
    };

    floatx4 acc[8][4];
#pragma unroll
    for (int i = 0; i < 8; i++)
#pragma unroll
        for (int j = 0; j < 4; j++) acc[i][j] = (floatx4){0.f, 0.f, 0.f, 0.f};

    const int nt = K >> 6, ngrp = nt >> 1;

    // prologue: T0 full + T1.{B0,B1,A0}; vmcnt(6) forces all 8 T0 loads done
    STAGE(0, 0, 0); STAGE(0, 1, 0); STAGE(0, 2, 0); STAGE(0, 3, 0);
    WAITVM(4);
    STAGE(1, 2, 1); STAGE(1, 3, 1); STAGE(1, 0, 1);
    WAITVM(6);
    BARRIER();

    bhalf8 aR[4][2], bR[4][2];

    for (int g = 0; g < ngrp; ++g) {
        const bool st = (g < ngrp - 1);
        const int t2 = 2 * g + 2, t3 = 2 * g + 3;

        // ---- phase 1 (tile 2g, buf0): A mf0-3, B nf0-1 (+nf2-3 for B0 waves)
#pragma unroll
        for (int mf = 0; mf < 4; mf++) { aR[mf][0] = LDA8(0, mf, 0); aR[mf][1] = LDA8(0, mf, 1); }
#pragma unroll
        for (int nf = 0; nf < 2; nf++) { bR[nf][0] = LDB8(0, nf, 0); bR[nf][1] = LDB8(0, nf, 1); }
        if (!(wave & 2)) {
#pragma unroll
            for (int nf = 2; nf < 4; nf++) { bR[nf][0] = LDB8(0, nf, 0); bR[nf][1] = LDB8(0, nf, 1); }
        }
        STAGE(2 * g + 1, 1, 1);          // T(2g+1).A1 -> buf1
        BARRIER(); WAITLGKM();
        __builtin_amdgcn_s_setprio(1);
        QUAD(0, 0);
        __builtin_amdgcn_s_setprio(0);
        BARRIER();

        // ---- phase 2: B1-waves read nf2-3; stage T2.B0 (buf0.B0 last read ph1)
        if (wave & 2) {
#pragma unroll
            for (int nf = 2; nf < 4; nf++) { bR[nf][0] = LDB8(0, nf, 0); bR[nf][1] = LDB8(0, nf, 1); }
        }
        if (st) STAGE(t2, 2, 0);
        BARRIER(); WAITLGKM();
        __builtin_amdgcn_s_setprio(1);
        QUAD(0, 2);
        __builtin_amdgcn_s_setprio(0);
        BARRIER();

        // ---- phase 3: A mf4-7; stage T2.B1 (buf0.B1 last read ph2)
#pragma unroll
        for (int mf = 4; mf < 8; mf++) { aR[mf & 3][0] = LDA8(0, mf, 0); aR[mf & 3][1] = LDA8(0, mf, 1); }
        if (st) STAGE(t2, 3, 0);
        BARRIER(); WAITLGKM();
        __builtin_amdgcn_s_setprio(1);
        QUAD(4, 0);
        __builtin_amdgcn_s_setprio(0);
        BARRIER();

        // ---- phase 4: stage T2.A0 (buf0.A0 last read ph3); boundary vmcnt
        if (st) STAGE(t2, 0, 0);
        BARRIER();
        __builtin_amdgcn_s_setprio(1);
        QUAD(4, 2);
        __builtin_amdgcn_s_setprio(0);
        if (st) { WAITVM(6); } else { WAITVM(0); }
        BARRIER();

        // ---- phase 5 (tile 2g+1, buf1): stage T2.A1 (buf0.A1 last read ph3)
#pragma unroll
        for (int mf = 0; mf < 4; mf++) { aR[mf][0] = LDA8(1, mf, 0); aR[mf][1] = LDA8(1, mf, 1); }
#pragma unroll
        for (int nf = 0; nf < 2; nf++) { bR[nf][0] = LDB8(1, nf, 0); bR[nf][1] = LDB8(1, nf, 1); }
        if (!(wave & 2)) {
#pragma unroll
            for (int nf = 2; nf < 4; nf++) { bR[nf][0] = LDB8(1, nf, 0); bR[nf][1] = LDB8(1, nf, 1); }
        }
        if (st) STAGE(t2, 1, 0);
        BARRIER(); WAITLGKM();
        __builtin_amdgcn_s_setprio(1);
        QUAD(0, 0);
        __builtin_amdgcn_s_setprio(0);
        BARRIER();

        // ---- phase 6: stage T3.B0 (buf1.B0 last read ph5)
        if (wave & 2) {
#pragma unroll
            for (int nf = 2; nf < 4; nf++) { bR[nf][0] = LDB8(1, nf, 0); bR[nf][1] = LDB8(1, nf, 1); }
        }
        if (st) STAGE(t3, 2, 1);
        BARRIER(); WAITLGKM();
        __builtin_amdgcn_s_setprio(1);
        QUAD(0, 2);
        __builtin_amdgcn_s_setprio(0);
        BARRIER();

        // ---- phase 7: stage T3.B1 (buf1.B1 last read ph6)
#pragma unroll
        for (int mf = 4; mf < 8; mf++) { aR[mf & 3][0] = LDA8(1, mf, 0); aR[mf & 3][1] = LDA8(1, mf, 1); }
        if (st) STAGE(t3, 3, 1);
        BARRIER(); WAITLGKM();
        __builtin_amdgcn_s_setprio(1);
        QUAD(4, 0);
        __builtin_amdgcn_s_setprio(0);
        BARRIER();

        // ---- phase 8: stage T3.A0 (buf1.A0 last read ph7); boundary vmcnt
        if (st) STAGE(t3, 0, 1);
        BARRIER();
        __builtin_amdgcn_s_setprio(1);
        QUAD(4, 2);
        __builtin_amdgcn_s_setprio(0);
        if (st) { WAITVM(6); }
        BARRIER();
    }

    // ---- epilogue
    const int wm = (wave >> 2) * 128, wn = (wave & 3) * 64;
    if (SPLITK) {
        float* Ob = outF + (long)zz * cStride;   // [bz][kh] partial layout
#pragma unroll
        for (int nf = 0; nf < 4; nf++) {
            const int col = bn + wn + nf * 16 + lr;
#pragma unroll
            for (int mf = 0; mf < 8; mf++) {
                const int row0 = bm + wm + mf * 16 + (lane >> 4) * 4;
#pragma unroll
                for (int r = 0; r < 4; r++)
                    Ob[(long)(row0 + r) * N + col] = acc[mf][nf][r] * scale;
            }
        }
        return;
    }
    if (RESID) {
        float* Ob = outF + (long)zz * cStride;
        const float* Xb = resid + (long)zz * cStride;
#pragma unroll
        for (int nf = 0; nf < 4; nf++) {
            const int col = bn + wn + nf * 16 + lr;
#pragma unroll
            for (int mf = 0; mf < 8; mf++) {
                const int row0 = bm + wm + mf * 16 + (lane >> 4) * 4;
                const long a = (long)col * M + row0;
                float4 xv = *(const float4*)&Xb[a];
                float4 ov;
                ov.x = acc[mf][nf][0] * scale + xv.x;
                ov.y = acc[mf][nf][1] * scale + xv.y;
                ov.z = acc[mf][nf][2] * scale + xv.z;
                ov.w = acc[mf][nf][3] * scale + xv.w;
                *(float4*)&Ob[a] = ov;
            }
        }
        return;
    }
    BF* Cb = C + (long)zz * cStride;
#pragma unroll
    for (int nf = 0; nf < 4; nf++) {
        const int col = bn + wn + nf * 16 + lr;
        const float bv = BIAS ? bias[col] : 0.0f;
#pragma unroll
        for (int mf = 0; mf < 8; mf++) {
            const int row0 = bm + wm + mf * 16 + (lane >> 4) * 4;
#pragma unroll
            for (int r = 0; r < 4; r++) {
                float v = acc[mf][nf][r] * scale + bv;
                if (TRANS) Cb[(long)col * M + row0 + r] = __float2bfloat16(v);
                else       Cb[(long)(row0 + r) * N + col] = __float2bfloat16(v);
            }
        }
    }
}

// ---------------------------------------------------------------------------
// split-K reduce: q[bz][e] = bf16(P[bz][0][e] + P[bz][1][e])
__global__ __launch_bounds__(256) void splitk_reduce(const float* __restrict__ P,
                                                     BF* __restrict__ dst,
                                                     long perBatch) {
    const long off = ((long)blockIdx.x * 256 + threadIdx.x) * 4;
    const float* p0 = P + (long)blockIdx.y * 2 * perBatch;
    float4 a = *(const float4*)&p0[off];
    float4 b = *(const float4*)&p0[perBatch + off];
    BF* d = dst + (long)blockIdx.y * perBatch + off;
    short4 o;
    o.x = f2b(a.x + b.x);
    o.y = f2b(a.y + b.y);
    o.z = f2b(a.z + b.z);
    o.w = f2b(a.w + b.w);
    *(short4*)d = o;
}

// ---------------------------------------------------------------------------
// GEMM 128x128 tile, BK=32 (m97-style) — fallback for PV at chunk==2.
// ---------------------------------------------------------------------------
template <bool BIAS, bool TRANS>
__global__ __launch_bounds__(256, 2) void gemm128(
    const BF* __restrict__ A, long aStride,
    const BF* __restrict__ Bm, long bStride,
    BF* __restrict__ C, long cStride,
    const float* __restrict__ bias,
    int M, int N, int K, float scale)
{
    __shared__ __align__(16) BF sA[128 * 32];
    __shared__ __align__(16) BF sB[128 * 32];
    const int tid = threadIdx.x;
    const int wave = tid >> 6, lane = tid & 63;
    int bxi = blockIdx.x, byi = blockIdx.y;
    xcd_swizzle(bxi, byi);
    const int bm = byi * 128, bn = bxi * 128;
    const BF* Ab = A + (long)blockIdx.z * aStride + (long)bm * K;
    const BF* Bb = Bm + (long)blockIdx.z * bStride + (long)bn * K;

    const int srow = wave * 32 + (lane >> 2);
    const int sk = (lane & 3) * 8;
    const BF* gA0 = Ab + (long)srow * K + sk;
    const BF* gA1 = gA0 + (long)16 * K;
    const BF* gB0 = Bb + (long)srow * K + sk;
    const BF* gB1 = gB0 + (long)16 * K;
    BF* lA0 = &sA[(wave * 32) * 32];
    BF* lA1 = &sA[(wave * 32 + 16) * 32];
    BF* lB0 = &sB[(wave * 32) * 32];
    BF* lB1 = &sB[(wave * 32 + 16) * 32];

    floatx4 acc[4][4];
#pragma unroll
    for (int i = 0; i < 4; i++)
#pragma unroll
        for (int j = 0; j < 4; j++) acc[i][j] = (floatx4){0.f, 0.f, 0.f, 0.f};

    const int wm = (wave >> 1) * 64, wn = (wave & 1) * 64;
    const int lr = lane & 15, lk = (lane >> 4) * 8;

    for (int k0 = 0; k0 < K; k0 += 32) {
        __syncthreads();
        gload16(gA0 + k0, lA0);
        gload16(gA1 + k0, lA1);
        gload16(gB0 + k0, lB0);
        gload16(gB1 + k0, lB1);
        __syncthreads();
        bhalf8 af[4], bfr[4];
#pragma unroll
        for (int i = 0; i < 4; i++)
            af[i] = *(const bhalf8*)&sA[(wm + i * 16 + lr) * 32 + lk];
#pragma unroll
        for (int i = 0; i < 4; i++)
            bfr[i] = *(const bhalf8*)&sB[(wn + i * 16 + lr) * 32 + lk];
#pragma unroll
        for (int mi = 0; mi < 4; mi++)
#pragma unroll
            for (int ni = 0; ni < 4; ni++)
                acc[mi][ni] = __builtin_amdgcn_mfma_f32_16x16x32_bf16(
                    af[mi], bfr[ni], acc[mi][ni], 0, 0, 0);
    }

    BF* Cb = C + (long)blockIdx.z * cStride;
#pragma unroll
    for (int ni = 0; ni < 4; ni++) {
        const int col = bn + wn + ni * 16 + lr;
        const float bv = BIAS ? bias[col] : 0.0f;
#pragma unroll
        for (int mi = 0; mi < 4; mi++) {
            const int row0 = bm + wm + mi * 16 + (lane >> 4) * 4;
#pragma unroll
            for (int r = 0; r < 4; r++) {
                float v = acc[mi][ni][r] * scale + bv;
                if (TRANS) Cb[(long)col * M + row0 + r] = __float2bfloat16(v);
                else       Cb[(long)(row0 + r) * N + col] = __float2bfloat16(v);
            }
        }
    }
}

// ---------------------------------------------------------------------------
// GEMM 64(M)x128(N) tile — fallback for PV at chunk==1.
// ---------------------------------------------------------------------------
__global__ __launch_bounds__(256, 2) void gemm64(
    const BF* __restrict__ A, long aStride,
    const BF* __restrict__ Bm, long bStride,
    BF* __restrict__ C, long cStride,
    int N, int K, float scale)
{
    __shared__ __align__(16) BF sA[64 * 32];
    __shared__ __align__(16) BF sB[128 * 32];
    const int tid = threadIdx.x;
    const int wave = tid >> 6, lane = tid & 63;
    int bxi = blockIdx.x, byi = blockIdx.y;
    xcd_swizzle(bxi, byi);
    const int bm = byi * 64, bn = bxi * 128;
    const BF* Ab = A + (long)blockIdx.z * aStride + (long)bm * K;
    const BF* Bb = Bm + (long)blockIdx.z * bStride + (long)bn * K;

    const int rowoff = lane >> 2, sk = (lane & 3) * 8;
    const BF* gA0 = Ab + (long)(wave * 16 + rowoff) * K + sk;
    const BF* gB0 = Bb + (long)(wave * 32 + rowoff) * K + sk;
    const BF* gB1 = gB0 + (long)16 * K;
    BF* lA0 = &sA[(wave * 16) * 32];
    BF* lB0 = &sB[(wave * 32) * 32];
    BF* lB1 = &sB[(wave * 32 + 16) * 32];

    floatx4 acc[2][4];
#pragma unroll
    for (int i = 0; i < 2; i++)
#pragma unroll
        for (int j = 0; j < 4; j++) acc[i][j] = (floatx4){0.f, 0.f, 0.f, 0.f};

    const int wm = (wave >> 1) * 32, wn = (wave & 1) * 64;
    const int lr = lane & 15, lk = (lane >> 4) * 8;

    for (int k0 = 0; k0 < K; k0 += 32) {
        __syncthreads();
        gload16(gA0 + k0, lA0);
        gload16(gB0 + k0, lB0);
        gload16(gB1 + k0, lB1);
        __syncthreads();
        bhalf8 af[2], bfr[4];
#pragma unroll
        for (int i = 0; i < 2; i++)
            af[i] = *(const bhalf8*)&sA[(wm + i * 16 + lr) * 32 + lk];
#pragma unroll
        for (int i = 0; i < 4; i++)
            bfr[i] = *(const bhalf8*)&sB[(wn + i * 16 + lr) * 32 + lk];
#pragma unroll
        for (int mi = 0; mi < 2; mi++)
#pragma unroll
            for (int ni = 0; ni < 4; ni++)
                acc[mi][ni] = __builtin_amdgcn_mfma_f32_16x16x32_bf16(
                    af[mi], bfr[ni], acc[mi][ni], 0, 0, 0);
    }

    BF* Cb = C + (long)blockIdx.z * cStride;
#pragma unroll
    for (int ni = 0; ni < 4; ni++) {
        const int col = bn + wn + ni * 16 + lr;
#pragma unroll
        for (int mi = 0; mi < 2; mi++) {
            const int row0 = bm + wm + mi * 16 + (lane >> 4) * 4;
#pragma unroll
            for (int r = 0; r < 4; r++)
                Cb[(long)(row0 + r) * N + col] = __float2bfloat16(acc[mi][ni][r] * scale);
        }
    }
}

// ---------------------------------------------------------------------------
__global__ __launch_bounds__(256) void softmax4096(BF* __restrict__ S) {
    const long base = (long)blockIdx.x * 4096 + threadIdx.x * 16;
    const int tid = threadIdx.x, w = tid >> 6;
    bhalf8 u = *(bhalf8*)&S[base];
    bhalf8 u2 = *(bhalf8*)&S[base + 8];
    float v[16];
    float m = -1e30f;
#pragma unroll
    for (int j = 0; j < 8; j++) { v[j] = b2f(u[j]); v[8 + j] = b2f(u2[j]); }
#pragma unroll
    for (int j = 0; j < 16; j++) m = fmaxf(m, v[j]);
#pragma unroll
    for (int o = 32; o; o >>= 1) m = fmaxf(m, __shfl_xor(m, o));
    __shared__ float rm[4], rs[4];
    if ((tid & 63) == 0) rm[w] = m;
    __syncthreads();
    m = fmaxf(fmaxf(rm[0], rm[1]), fmaxf(rm[2], rm[3]));
    float s = 0.f;
#pragma unroll
    for (int j = 0; j < 16; j++) { v[j] = __expf(v[j] - m); s += v[j]; }
#pragma unroll
    for (int o = 32; o; o >>= 1) s += __shfl_xor(s, o);
    if ((tid & 63) == 0) rs[w] = s;
    __syncthreads();
    s = rs[0] + rs[1] + rs[2] + rs[3];
    const float inv = 1.0f / s;
#pragma unroll
    for (int j = 0; j < 8; j++) { u[j] = f2b(v[j] * inv); u2[j] = f2b(v[8 + j] * inv); }
    *(bhalf8*)&S[base] = u;
    *(bhalf8*)&S[base + 8] = u2;
}

// ---------------------------------------------------------------------------
extern "C" void kernel_launch(void* const* d_in, const int* in_sizes, int n_in,
                              void* d_out, int out_size, void* d_ws, size_t ws_size,
                              hipStream_t stream) {
    const float* x     = (const float*)d_in[0];
    const float* gamma = (const float*)d_in[1];
    const float* beta  = (const float*)d_in[2];
    const float* Wq    = (const float*)d_in[3];
    const float* bq    = (const float*)d_in[4];
    const float* Wk    = (const float*)d_in[5];
    const float* bk    = (const float*)d_in[6];
    const float* Wv    = (const float*)d_in[7];
    const float* bv    = (const float*)d_in[8];
    const float* Wo    = (const float*)d_in[9];
    float* out = (float*)d_out;

    const long ACTB = (long)NHW * NC;
    const long SB   = (long)NHW * NHW;
    const long WSZ  = (long)NC * NC;

    char* ws = (char*)d_ws;
    float* stats = (float*)ws;
    BF* wb = (BF*)(ws + 4096);
    BF* q  = wb + 4 * WSZ;
    BF* kk = q + NB * ACTB;
    BF* vT = kk + NB * ACTB;
    BF* R  = vT + NB * ACTB;
    BF* n = R;   // live: GN -> QKV GEMMs
    BF* S = R;   // live: attention chunks

    const size_t base_need = 4096ull + (size_t)4 * WSZ * 2 + (size_t)3 * NB * ACTB * 2;
    long sroom = (ws_size > base_need) ? (long)((ws_size - base_need) / (SB * 2)) : 1;
    int chunk = (int)(sroom < 1 ? 1 : (sroom > NB ? NB : sroom));
    while (NB % chunk) chunk--;              // 8,4,2,1

    // split-K PV partials (f32, [bz][kh][ACTB]) after S, if room
    float* Pf = (float*)(R + (long)chunk * SB);
    const size_t splitNeed = base_need + (size_t)chunk * SB * 2
                           + (size_t)chunk * 2 * ACTB * 4;
    const bool doSplit = (chunk >= 2) && (ws_size >= splitNeed);

    f2b_convert4<<<1024, 256, 0, stream>>>(Wq, Wk, Wv, Wo, wb);

    gn_stats<<<NB * NG, 256, 0, stream>>>(x, stats);
    gn_apply<<<dim3(NHW / 64, NC / 64, NB), 256, 0, stream>>>(x, gamma, beta, stats, n);

    gemm256<true, false, false, false><<<dim3(NC / 256, NHW / 256, NB), 512, 0, stream>>>(
        n, ACTB, wb + 0 * WSZ, 0, q, ACTB, bq, nullptr, nullptr, NHW, NC, NC, 1.0f, NC, NC);
    gemm256<true, false, false, false><<<dim3(NC / 256, NHW / 256, NB), 512, 0, stream>>>(
        n, ACTB, wb + 1 * WSZ, 0, kk, ACTB, bk, nullptr, nullptr, NHW, NC, NC, 1.0f, NC, NC);
    gemm256<true, true, false, false><<<dim3(NC / 256, NHW / 256, NB), 512, 0, stream>>>(
        n, ACTB, wb + 2 * WSZ, 0, vT, ACTB, bv, nullptr, nullptr, NHW, NC, NC, 1.0f, NC, NC);

    const float iscl = 0.044194173824159216f;  // 1/sqrt(512)
    for (int b0 = 0; b0 < NB; b0 += chunk) {
        gemm256<false, false, false, false><<<dim3(NHW / 256, NHW / 256, chunk), 512, 0, stream>>>(
            q + b0 * ACTB, ACTB, kk + b0 * ACTB, ACTB, S, SB, nullptr, nullptr, nullptr,
            NHW, NHW, NC, iscl, NC, NC);
        softmax4096<<<NHW * chunk, 256, 0, stream>>>(S);
        if (doSplit) {
            // PV split-K=2: z = 2*bz+kh, each half K=2048; f32 partials, then reduce
            gemm256<false, false, false, true><<<dim3(NC / 256, NHW / 256, chunk * 2), 512, 0, stream>>>(
                S, SB, vT + b0 * ACTB, ACTB, nullptr, ACTB, nullptr, nullptr, Pf,
                NHW, NC, NHW / 2, 1.0f, NHW, NHW);
            splitk_reduce<<<dim3((unsigned)(ACTB / 1024), chunk), 256, 0, stream>>>(
                Pf, q + b0 * ACTB, ACTB);
        } else if (chunk >= 4) {
            gemm256<false, false, false, false><<<dim3(NC / 256, NHW / 256, chunk), 512, 0, stream>>>(
                S, SB, vT + b0 * ACTB, ACTB, q + b0 * ACTB, ACTB, nullptr, nullptr, nullptr,
                NHW, NC, NHW, 1.0f, NHW, NHW);
        } else if (chunk == 2) {
            gemm128<false, false><<<dim3(NC / 128, NHW / 128, chunk), 256, 0, stream>>>(
                S, SB, vT + b0 * ACTB, ACTB, q + b0 * ACTB, ACTB, nullptr, NHW, NC, NHW, 1.0f);
        } else {
            gemm64<<<dim3(NC / 128, NHW / 64, chunk), 256, 0, stream>>>(
                S, SB, vT + b0 * ACTB, ACTB, q + b0 * ACTB, ACTB, NC, NHW, 1.0f);
        }
    }

    // final projection fused with transpose + residual add (writes f32 output)
    gemm256<false, true, true, false><<<dim3(NC / 256, NHW / 256, NB), 512, 0, stream>>>(
        q, ACTB, wb + 3 * WSZ, 0, nullptr, ACTB, nullptr, x, out, NHW, NC, NC, 1.0f, NC, NC);
}

// Round 6
// 784.320 us; speedup vs baseline: 1.0519x; 1.0015x over previous
//
#include <hip/hip_runtime.h>
#include <hip/hip_bf16.h>
#include <cstdint>
#include <cstddef>

typedef __hip_bfloat16 BF;
typedef __attribute__((ext_vector_type(8))) short bhalf8;   // 8 bf16 (MFMA A/B frag)
typedef __attribute__((ext_vector_type(4))) float floatx4;  // MFMA C/D frag

#define NB 8
#define NC 512
#define NHW 4096
#define NG 32

__device__ __forceinline__ float b2f(short h) {
    union { unsigned u; float f; } c;
    c.u = ((unsigned)(unsigned short)h) << 16;
    return c.f;
}
__device__ __forceinline__ short f2b(float f) {
    __hip_bfloat16 h = __float2bfloat16(f);
    short s;
    __builtin_memcpy(&s, &h, 2);
    return s;
}

// 16B global -> LDS direct (wave-uniform LDS base + lane*16)
__device__ __forceinline__ void gload16(const BF* g, BF* l) {
    __builtin_amdgcn_global_load_lds(
        (const __attribute__((address_space(1))) void*)g,
        (__attribute__((address_space(3))) void*)l, 16, 0, 0);
}

__device__ __forceinline__ void BARRIER() {
    asm volatile("" ::: "memory");
    __builtin_amdgcn_s_barrier();
    asm volatile("" ::: "memory");
}
#define WAITVM(N) asm volatile("s_waitcnt vmcnt(" #N ")" ::: "memory")
#define WAITLGKM0() asm volatile("s_waitcnt lgkmcnt(0)" ::: "memory")
#define WAITLGKM8() asm volatile("s_waitcnt lgkmcnt(8)" ::: "memory")
#define SB0() __builtin_amdgcn_sched_barrier(0)

// compiler-invisible LDS read: no alias vs global_load_lds -> no inserted
// vmcnt drains (the counted-vmcnt pipeline survives). IMM must be a literal.
// "=&v" early-clobber: result tuple can never overlap the live base VGPR.
#define DSR(dst, base, IMM) \
    asm volatile("ds_read_b128 %0, %1 offset:" #IMM : "=&v"(dst) : "v"(base))

// T1: bijective XCD-aware tile swizzle (nwg % 8 == 0 for all our grids)
__device__ __forceinline__ void xcd_swizzle(int& bx, int& by) {
    const int gx = gridDim.x;
    const int nwg = gx * gridDim.y;
    if ((nwg & 7) == 0) {
        const int lin = by * gx + bx;
        const int cpx = nwg >> 3;
        const int s = (lin & 7) * cpx + (lin >> 3);
        bx = s % gx;
        by = s / gx;
    }
}

// ---------------------------------------------------------------------------
__global__ __launch_bounds__(256) void f2b_convert4(const float* __restrict__ s0,
                                                    const float* __restrict__ s1,
                                                    const float* __restrict__ s2,
                                                    const float* __restrict__ s3,
                                                    BF* __restrict__ dst) {
    const int which = blockIdx.x >> 8;
    const float* src = (which == 0) ? s0 : (which == 1) ? s1 : (which == 2) ? s2 : s3;
    BF* d = dst + (long)which * (NC * NC);
    const int i = ((blockIdx.x & 255) * 256 + threadIdx.x) * 4;
    float4 v = *(const float4*)&src[i];
    d[i]     = __float2bfloat16(v.x);
    d[i + 1] = __float2bfloat16(v.y);
    d[i + 2] = __float2bfloat16(v.z);
    d[i + 3] = __float2bfloat16(v.w);
}

// ---------------------------------------------------------------------------
__global__ __launch_bounds__(256) void gn_stats(const float* __restrict__ x,
                                                float* __restrict__ stats) {
    const int bg = blockIdx.x;
    const long base = (long)bg * 65536;
    float s = 0.f, q = 0.f;
    for (int i = threadIdx.x * 4; i < 65536; i += 256 * 4) {
        float4 v4 = *(const float4*)&x[base + i];
        s += v4.x + v4.y + v4.z + v4.w;
        q += v4.x * v4.x + v4.y * v4.y + v4.z * v4.z + v4.w * v4.w;
    }
#pragma unroll
    for (int o = 32; o; o >>= 1) { s += __shfl_down(s, o); q += __shfl_down(q, o); }
    __shared__ float rs[4], rq[4];
    const int w = threadIdx.x >> 6;
    if ((threadIdx.x & 63) == 0) { rs[w] = s; rq[w] = q; }
    __syncthreads();
    if (threadIdx.x == 0) {
        s = rs[0] + rs[1] + rs[2] + rs[3];
        q = rq[0] + rq[1] + rq[2] + rq[3];
        float mean = s * (1.f / 65536.f);
        float var = q * (1.f / 65536.f) - mean * mean;
        stats[2 * bg]     = mean;
        stats[2 * bg + 1] = rsqrtf(fmaxf(var, 0.f) + 1e-6f);
    }
}

// ---------------------------------------------------------------------------
__global__ __launch_bounds__(256) void gn_apply(const float* __restrict__ x,
                                                const float* __restrict__ gamma,
                                                const float* __restrict__ beta,
                                                const float* __restrict__ stats,
                                                BF* __restrict__ n) {
    __shared__ float tile[64][65];
    const int b = blockIdx.z, c0 = blockIdx.y * 64, s0 = blockIdx.x * 64;
    const long xbase = ((long)b * NC + c0) * NHW + s0;
#pragma unroll
    for (int i = 0; i < 16; i++) {
        int lin = i * 256 + threadIdx.x;
        int cl = lin >> 6, sl = lin & 63;
        int c = c0 + cl;
        float2 mr = ((const float2*)stats)[b * NG + (c >> 4)];
        float v = x[xbase + (long)cl * NHW + sl];
        v = (v - mr.x) * mr.y * gamma[c] + beta[c];
        tile[cl][sl] = v;
    }
    __syncthreads();
    const long nbase = ((long)b * NHW + s0) * NC + c0;
#pragma unroll
    for (int i = 0; i < 16; i++) {
        int lin = i * 256 + threadIdx.x;
        int sl = lin >> 6, cl = lin & 63;
        n[nbase + (long)sl * NC + cl] = __float2bfloat16(tile[cl][sl]);
    }
}

// ---------------------------------------------------------------------------
// 256x256 8-phase GEMM (T1+T2+T3+T4+T5). C[m][n] = scale*sum_k A[m][k]*B[n][k]
// (+bias[n]). A [M,K] lda, B [N,K] ldb, K-contig bf16. BK=64, 8 waves (2Mx4N).
// LDS 128KB: 2 dbuf x {A0,A1,B0,B1} 16KB regions; T2 swizzle (conflicts=0, R3).
// K-loop LDS reads are inline-asm ds_read_b128 (compiler-invisible) so hipcc
// cannot insert alias-driven vmcnt(0) drains that defeat the counted-vmcnt
// pipeline (R4 theory). Explicit lgkmcnt(0)+sched_barrier(0) before MFMA
// (rule #18). vmcnt(6) only at phases 4/8.
// ---------------------------------------------------------------------------
#define RD_A_LO(b0, b1) { DSR(aR[0][0],b0,0);    DSR(aR[1][0],b0,2048); \
                          DSR(aR[2][0],b0,4096); DSR(aR[3][0],b0,6144); \
                          DSR(aR[0][1],b1,0);    DSR(aR[1][1],b1,2048); \
                          DSR(aR[2][1],b1,4096); DSR(aR[3][1],b1,6144); }
#define RD_A_HI(b0, b1) { DSR(aR[0][0],b0,8192);  DSR(aR[1][0],b0,10240); \
                          DSR(aR[2][0],b0,12288); DSR(aR[3][0],b0,14336); \
                          DSR(aR[0][1],b1,8192);  DSR(aR[1][1],b1,10240); \
                          DSR(aR[2][1],b1,12288); DSR(aR[3][1],b1,14336); }
#define RD_B_LO(b0, b1) { DSR(bR[0][0],b0,0);    DSR(bR[1][0],b0,2048); \
                          DSR(bR[0][1],b1,0);    DSR(bR[1][1],b1,2048); }
#define RD_B_HI(b0, b1) { DSR(bR[2][0],b0,4096); DSR(bR[3][0],b0,6144); \
                          DSR(bR[2][1],b1,4096); DSR(bR[3][1],b1,6144); }
#define QUAD(M0, N0)                                                                     \
    {                                                                                    \
        _Pragma("unroll") for (int ks = 0; ks < 2; ks++)                                 \
            _Pragma("unroll") for (int mf = (M0); mf < (M0) + 4; mf++)                   \
                _Pragma("unroll") for (int nf = (N0); nf < (N0) + 2; nf++)               \
                    acc[mf][nf] = __builtin_amdgcn_mfma_f32_16x16x32_bf16(               \
                        aR[mf & 3][ks], bR[nf][ks], acc[mf][nf], 0, 0, 0);               \
    }

template <bool BIAS, bool TRANS, bool RESID, bool SPLITK>
__global__ __launch_bounds__(512) void gemm256(
    const BF* __restrict__ A, long aStride,
    const BF* __restrict__ Bm, long bStride,
    BF* __restrict__ C, long cStride,
    const float* __restrict__ bias,
    const float* __restrict__ resid, float* __restrict__ outF,
    int M, int N, int K, float scale, long lda, long ldb)
{
    __shared__ __align__(16) char sL[131072];
    const int tid = threadIdx.x;
    const int wave = tid >> 6, lane = tid & 63;
    int bxi = blockIdx.x, byi = blockIdx.y;
    xcd_swizzle(bxi, byi);
    const int bm = byi * 256, bn = bxi * 256;
    const int zz = blockIdx.z;
    const int bz = SPLITK ? (zz >> 1) : zz;
    const int kh = SPLITK ? (zz & 1) : 0;
    const BF* Ab = A + (long)bz * aStride + (long)kh * K + (long)bm * lda;
    const BF* Bb = Bm + (long)bz * bStride + (long)kh * K + (long)bn * ldb;

    // staging: LDS dest linear; global source carries the inverse swizzle
    const int d0 = tid * 16, d1 = 8192 + tid * 16;
    const int r0 = d0 >> 7, r1 = d1 >> 7;
    const int c0s = ((d0 ^ ((r0 & 7) << 4)) & 127) >> 1;
    const int c1s = ((d1 ^ ((r1 & 7) << 4)) & 127) >> 1;
    const long sA0 = (long)r0 * lda + c0s, sA1 = (long)r1 * lda + c1s;
    const long sB0 = (long)r0 * ldb + c0s, sB1 = (long)r1 * ldb + c1s;
    const int lds0 = wave * 1024;           // wave-uniform; HW adds lane*16
    const int lds1 = 8192 + wave * 1024;

    // frag ds_read base addrs with the same swizzle (lane-constant fold)
    const int lr = lane & 15, lk2 = (lane >> 4) * 16;
    const int swz = (lr & 7) << 4;
    const int sb0 = lr * 128 + (lk2 ^ swz);          // ks=0
    const int sb1 = lr * 128 + ((lk2 + 64) ^ swz);   // ks=1
    const int aReg = (wave >> 2) * 16384;
    const int bReg = (2 + ((wave >> 1) & 1)) * 16384 + (wave & 1) * 8192;
    // buf0 / buf1 base registers (buf1 = +65536; ds offset imm is 16-bit)
    const int aI0 = aReg + sb0, aI1 = aReg + sb1;
    const int bI0 = bReg + sb0, bI1 = bReg + sb1;
    const int aJ0 = aI0 + 65536, aJ1 = aI1 + 65536;
    const int bJ0 = bI0 + 65536, bJ1 = bI1 + 65536;

    auto STAGE = [&](int t, int region, int dbuf) {
        const bool isA = region < 2;
        const long ld = isA ? lda : ldb;
        const BF* g = (isA ? (Ab + (long)region * 128 * ld)
                           : (Bb + (long)(region - 2) * 128 * ld)) + (long)t * 64;
        char* lb = sL + dbuf * 65536 + region * 16384;
        gload16(g + (isA ? sA0 : sB0), (BF*)(lb + lds0));
        gload16(g + (isA ? sA1 : sB1), (BF*)(lb + lds1));
    };

    floatx4 acc[8][4];
#pragma unroll
    for (int i = 0; i < 8; i++)
#pragma unroll
        for (int j = 0; j < 4; j++) acc[i][j] = (floatx4){0.f, 0.f, 0.f, 0.f};

    const int nt = K >> 6, ngrp = nt >> 1;

    // prologue: T0 full + T1.{B0,B1,A0}; vmcnt(6) forces all 8 T0 loads done
    STAGE(0, 0, 0); STAGE(0, 1, 0); STAGE(0, 2, 0); STAGE(0, 3, 0);
    WAITVM(4);
    STAGE(1, 2, 1); STAGE(1, 3, 1); STAGE(1, 0, 1);
    WAITVM(6);
    BARRIER();

    bhalf8 aR[4][2], bR[4][2];

    for (int g = 0; g < ngrp; ++g) {
        const bool st = (g < ngrp - 1);
        const int t2 = 2 * g + 2, t3 = 2 * g + 3;

        // ---- phase 1 (tile 2g, buf0): A mf0-3, B nf0-1 (+nf2-3 for B0 waves)
        RD_A_LO(aI0, aI1);
        RD_B_LO(bI0, bI1);
        if (!(wave & 2)) { RD_B_HI(bI0, bI1); }
        STAGE(2 * g + 1, 1, 1);          // T(2g+1).A1 -> buf1
        WAITLGKM8();
        BARRIER(); WAITLGKM0(); SB0();
        __builtin_amdgcn_s_setprio(1);
        QUAD(0, 0);
        SB0();
        __builtin_amdgcn_s_setprio(0);
        BARRIER();

        // ---- phase 2: B1-waves read nf2-3; stage T2.B0 (buf0.B0 last read ph1)
        if (wave & 2) { RD_B_HI(bI0, bI1); }
        if (st) STAGE(t2, 2, 0);
        BARRIER(); WAITLGKM0(); SB0();
        __builtin_amdgcn_s_setprio(1);
        QUAD(0, 2);
        SB0();
        __builtin_amdgcn_s_setprio(0);
        BARRIER();

        // ---- phase 3: A mf4-7; stage T2.B1 (buf0.B1 last read ph2)
        RD_A_HI(aI0, aI1);
        if (st) STAGE(t2, 3, 0);
        BARRIER(); WAITLGKM0(); SB0();
        __builtin_amdgcn_s_setprio(1);
        QUAD(4, 0);
        SB0();
        __builtin_amdgcn_s_setprio(0);
        BARRIER();

        // ---- phase 4: stage T2.A0 (buf0.A0 last read ph3); boundary vmcnt
        if (st) STAGE(t2, 0, 0);
        BARRIER(); SB0();
        __builtin_amdgcn_s_setprio(1);
        QUAD(4, 2);
        SB0();
        __builtin_amdgcn_s_setprio(0);
        if (st) { WAITVM(6); } else { WAITVM(0); }
        BARRIER();

        // ---- phase 5 (tile 2g+1, buf1): stage T2.A1 (buf0.A1 last read ph3)
        RD_A_LO(aJ0, aJ1);
        RD_B_LO(bJ0, bJ1);
        if (!(wave & 2)) { RD_B_HI(bJ0, bJ1); }
        if (st) STAGE(t2, 1, 0);
        WAITLGKM8();
        BARRIER(); WAITLGKM0(); SB0();
        __builtin_amdgcn_s_setprio(1);
        QUAD(0, 0);
        SB0();
        __builtin_amdgcn_s_setprio(0);
        BARRIER();

        // ---- phase 6: stage T3.B0 (buf1.B0 last read ph5)
        if (wave & 2) { RD_B_HI(bJ0, bJ1); }
        if (st) STAGE(t3, 2, 1);
        BARRIER(); WAITLGKM0(); SB0();
        __builtin_amdgcn_s_setprio(1);
        QUAD(0, 2);
        SB0();
        __builtin_amdgcn_s_setprio(0);
        BARRIER();

        // ---- phase 7: stage T3.B1 (buf1.B1 last read ph6)
        RD_A_HI(aJ0, aJ1);
        if (st) STAGE(t3, 3, 1);
        BARRIER(); WAITLGKM0(); SB0();
        __builtin_amdgcn_s_setprio(1);
        QUAD(4, 0);
        SB0();
        __builtin_amdgcn_s_setprio(0);
        BARRIER();

        // ---- phase 8: stage T3.A0 (buf1.A0 last read ph7); boundary vmcnt
        if (st) STAGE(t3, 0, 1);
        BARRIER(); SB0();
        __builtin_amdgcn_s_setprio(1);
        QUAD(4, 2);
        SB0();
        __builtin_amdgcn_s_setprio(0);
        if (st) { WAITVM(6); }
        BARRIER();
    }

    // ---- epilogue
    const int wm = (wave >> 2) * 128, wn = (wave & 3) * 64;
    if (SPLITK) {
        float* Ob = outF + (long)zz * cStride;   // [bz][kh] partial layout
#pragma unroll
        for (int nf = 0; nf < 4; nf++) {
            const int col = bn + wn + nf * 16 + lr;
#pragma unroll
            for (int mf = 0; mf < 8; mf++) {
                const int row0 = bm + wm + mf * 16 + (lane >> 4) * 4;
#pragma unroll
                for (int r = 0; r < 4; r++)
                    Ob[(long)(row0 + r) * N + col] = acc[mf][nf][r] * scale;
            }
        }
        return;
    }
    if (RESID) {
        float* Ob = outF + (long)zz * cStride;
        const float* Xb = resid + (long)zz * cStride;
#pragma unroll
        for (int nf = 0; nf < 4; nf++) {
            const int col = bn + wn + nf * 16 + lr;
#pragma unroll
            for (int mf = 0; mf < 8; mf++) {
                const int row0 = bm + wm + mf * 16 + (lane >> 4) * 4;
                const long a = (long)col * M + row0;
                float4 xv = *(const float4*)&Xb[a];
                float4 ov;
                ov.x = acc[mf][nf][0] * scale + xv.x;
                ov.y = acc[mf][nf][1] * scale + xv.y;
                ov.z = acc[mf][nf][2] * scale + xv.z;
                ov.w = acc[mf][nf][3] * scale + xv.w;
                *(float4*)&Ob[a] = ov;
            }
        }
        return;
    }
    BF* Cb = C + (long)zz * cStride;
#pragma unroll
    for (int nf = 0; nf < 4; nf++) {
        const int col = bn + wn + nf * 16 + lr;
        const float bv = BIAS ? bias[col] : 0.0f;
#pragma unroll
        for (int mf = 0; mf < 8; mf++) {
            const int row0 = bm + wm + mf * 16 + (lane >> 4) * 4;
#pragma unroll
            for (int r = 0; r < 4; r++) {
                float v = acc[mf][nf][r] * scale + bv;
                if (TRANS) Cb[(long)col * M + row0 + r] = __float2bfloat16(v);
                else       Cb[(long)(row0 + r) * N + col] = __float2bfloat16(v);
            }
        }
    }
}

// ---------------------------------------------------------------------------
// split-K reduce: q[bz][e] = bf16(P[bz][0][e] + P[bz][1][e])
__global__ __launch_bounds__(256) void splitk_reduce(const float* __restrict__ P,
                                                     BF* __restrict__ dst,
                                                     long perBatch) {
    const long off = ((long)blockIdx.x * 256 + threadIdx.x) * 4;
    const float* p0 = P + (long)blockIdx.y * 2 * perBatch;
    float4 a = *(const float4*)&p0[off];
    float4 b = *(const float4*)&p0[perBatch + off];
    BF* d = dst + (long)blockIdx.y * perBatch + off;
    short4 o;
    o.x = f2b(a.x + b.x);
    o.y = f2b(a.y + b.y);
    o.z = f2b(a.z + b.z);
    o.w = f2b(a.w + b.w);
    *(short4*)d = o;
}

// ---------------------------------------------------------------------------
// GEMM 128x128 tile, BK=32 (m97-style) — fallback for PV at chunk==2.
// ---------------------------------------------------------------------------
template <bool BIAS, bool TRANS>
__global__ __launch_bounds__(256, 2) void gemm128(
    const BF* __restrict__ A, long aStride,
    const BF* __restrict__ Bm, long bStride,
    BF* __restrict__ C, long cStride,
    const float* __restrict__ bias,
    int M, int N, int K, float scale)
{
    __shared__ __align__(16) BF sA[128 * 32];
    __shared__ __align__(16) BF sB[128 * 32];
    const int tid = threadIdx.x;
    const int wave = tid >> 6, lane = tid & 63;
    int bxi = blockIdx.x, byi = blockIdx.y;
    xcd_swizzle(bxi, byi);
    const int bm = byi * 128, bn = bxi * 128;
    const BF* Ab = A + (long)blockIdx.z * aStride + (long)bm * K;
    const BF* Bb = Bm + (long)blockIdx.z * bStride + (long)bn * K;

    const int srow = wave * 32 + (lane >> 2);
    const int sk = (lane & 3) * 8;
    const BF* gA0 = Ab + (long)srow * K + sk;
    const BF* gA1 = gA0 + (long)16 * K;
    const BF* gB0 = Bb + (long)srow * K + sk;
    const BF* gB1 = gB0 + (long)16 * K;
    BF* lA0 = &sA[(wave * 32) * 32];
    BF* lA1 = &sA[(wave * 32 + 16) * 32];
    BF* lB0 = &sB[(wave * 32) * 32];
    BF* lB1 = &sB[(wave * 32 + 16) * 32];

    floatx4 acc[4][4];
#pragma unroll
    for (int i = 0; i < 4; i++)
#pragma unroll
        for (int j = 0; j < 4; j++) acc[i][j] = (floatx4){0.f, 0.f, 0.f, 0.f};

    const int wm = (wave >> 1) * 64, wn = (wave & 1) * 64;
    const int lr = lane & 15, lk = (lane >> 4) * 8;

    for (int k0 = 0; k0 < K; k0 += 32) {
        __syncthreads();
        gload16(gA0 + k0, lA0);
        gload16(gA1 + k0, lA1);
        gload16(gB0 + k0, lB0);
        gload16(gB1 + k0, lB1);
        __syncthreads();
        bhalf8 af[4], bfr[4];
#pragma unroll
        for (int i = 0; i < 4; i++)
            af[i] = *(const bhalf8*)&sA[(wm + i * 16 + lr) * 32 + lk];
#pragma unroll
        for (int i = 0; i < 4; i++)
            bfr[i] = *(const bhalf8*)&sB[(wn + i * 16 + lr) * 32 + lk];
#pragma unroll
        for (int mi = 0; mi < 4; mi++)
#pragma unroll
            for (int ni = 0; ni < 4; ni++)
                acc[mi][ni] = __builtin_amdgcn_mfma_f32_16x16x32_bf16(
                    af[mi], bfr[ni], acc[mi][ni], 0, 0, 0);
    }

    BF* Cb = C + (long)blockIdx.z * cStride;
#pragma unroll
    for (int ni = 0; ni < 4; ni++) {
        const int col = bn + wn + ni * 16 + lr;
        const float bv = BIAS ? bias[col] : 0.0f;
#pragma unroll
        for (int mi = 0; mi < 4; mi++) {
            const int row0 = bm + wm + mi * 16 + (lane >> 4) * 4;
#pragma unroll
            for (int r = 0; r < 4; r++) {
                float v = acc[mi][ni][r] * scale + bv;
                if (TRANS) Cb[(long)col * M + row0 + r] = __float2bfloat16(v);
                else       Cb[(long)(row0 + r) * N + col] = __float2bfloat16(v);
            }
        }
    }
}

// ---------------------------------------------------------------------------
// GEMM 64(M)x128(N) tile — fallback for PV at chunk==1.
// ---------------------------------------------------------------------------
__global__ __launch_bounds__(256, 2) void gemm64(
    const BF* __restrict__ A, long aStride,
    const BF* __restrict__ Bm, long bStride,
    BF* __restrict__ C, long cStride,
    int N, int K, float scale)
{
    __shared__ __align__(16) BF sA[64 * 32];
    __shared__ __align__(16) BF sB[128 * 32];
    const int tid = threadIdx.x;
    const int wave = tid >> 6, lane = tid & 63;
    int bxi = blockIdx.x, byi = blockIdx.y;
    xcd_swizzle(bxi, byi);
    const int bm = byi * 64, bn = bxi * 128;
    const BF* Ab = A + (long)blockIdx.z * aStride + (long)bm * K;
    const BF* Bb = Bm + (long)blockIdx.z * bStride + (long)bn * K;

    const int rowoff = lane >> 2, sk = (lane & 3) * 8;
    const BF* gA0 = Ab + (long)(wave * 16 + rowoff) * K + sk;
    const BF* gB0 = Bb + (long)(wave * 32 + rowoff) * K + sk;
    const BF* gB1 = gB0 + (long)16 * K;
    BF* lA0 = &sA[(wave * 16) * 32];
    BF* lB0 = &sB[(wave * 32) * 32];
    BF* lB1 = &sB[(wave * 32 + 16) * 32];

    floatx4 acc[2][4];
#pragma unroll
    for (int i = 0; i < 2; i++)
#pragma unroll
        for (int j = 0; j < 4; j++) acc[i][j] = (floatx4){0.f, 0.f, 0.f, 0.f};

    const int wm = (wave >> 1) * 32, wn = (wave & 1) * 64;
    const int lr = lane & 15, lk = (lane >> 4) * 8;

    for (int k0 = 0; k0 < K; k0 += 32) {
        __syncthreads();
        gload16(gA0 + k0, lA0);
        gload16(gB0 + k0, lB0);
        gload16(gB1 + k0, lB1);
        __syncthreads();
        bhalf8 af[2], bfr[4];
#pragma unroll
        for (int i = 0; i < 2; i++)
            af[i] = *(const bhalf8*)&sA[(wm + i * 16 + lr) * 32 + lk];
#pragma unroll
        for (int i = 0; i < 4; i++)
            bfr[i] = *(const bhalf8*)&sB[(wn + i * 16 + lr) * 32 + lk];
#pragma unroll
        for (int mi = 0; mi < 2; mi++)
#pragma unroll
            for (int ni = 0; ni < 4; ni++)
                acc[mi][ni] = __builtin_amdgcn_mfma_f32_16x16x32_bf16(
                    af[mi], bfr[ni], acc[mi][ni], 0, 0, 0);
    }

    BF* Cb = C + (long)blockIdx.z * cStride;
#pragma unroll
    for (int ni = 0; ni < 4; ni++) {
        const int col = bn + wn + ni * 16 + lr;
#pragma unroll
        for (int mi = 0; mi < 2; mi++) {
            const int row0 = bm + wm + mi * 16 + (lane >> 4) * 4;
#pragma unroll
            for (int r = 0; r < 4; r++)
                Cb[(long)(row0 + r) * N + col] = __float2bfloat16(acc[mi][ni][r] * scale);
        }
    }
}

// ---------------------------------------------------------------------------
__global__ __launch_bounds__(256) void softmax4096(BF* __restrict__ S) {
    const long base = (long)blockIdx.x * 4096 + threadIdx.x * 16;
    const int tid = threadIdx.x, w = tid >> 6;
    bhalf8 u = *(bhalf8*)&S[base];
    bhalf8 u2 = *(bhalf8*)&S[base + 8];
    float v[16];
    float m = -1e30f;
#pragma unroll
    for (int j = 0; j < 8; j++) { v[j] = b2f(u[j]); v[8 + j] = b2f(u2[j]); }
#pragma unroll
    for (int j = 0; j < 16; j++) m = fmaxf(m, v[j]);
#pragma unroll
    for (int o = 32; o; o >>= 1) m = fmaxf(m, __shfl_xor(m, o));
    __shared__ float rm[4], rs[4];
    if ((tid & 63) == 0) rm[w] = m;
    __syncthreads();
    m = fmaxf(fmaxf(rm[0], rm[1]), fmaxf(rm[2], rm[3]));
    float s = 0.f;
#pragma unroll
    for (int j = 0; j < 16; j++) { v[j] = __expf(v[j] - m); s += v[j]; }
#pragma unroll
    for (int o = 32; o; o >>= 1) s += __shfl_xor(s, o);
    if ((tid & 63) == 0) rs[w] = s;
    __syncthreads();
    s = rs[0] + rs[1] + rs[2] + rs[3];
    const float inv = 1.0f / s;
#pragma unroll
    for (int j = 0; j < 8; j++) { u[j] = f2b(v[j] * inv); u2[j] = f2b(v[8 + j] * inv); }
    *(bhalf8*)&S[base] = u;
    *(bhalf8*)&S[base + 8] = u2;
}

// ---------------------------------------------------------------------------
extern "C" void kernel_launch(void* const* d_in, const int* in_sizes, int n_in,
                              void* d_out, int out_size, void* d_ws, size_t ws_size,
                              hipStream_t stream) {
    const float* x     = (const float*)d_in[0];
    const float* gamma = (const float*)d_in[1];
    const float* beta  = (const float*)d_in[2];
    const float* Wq    = (const float*)d_in[3];
    const float* bq    = (const float*)d_in[4];
    const float* Wk    = (const float*)d_in[5];
    const float* bk    = (const float*)d_in[6];
    const float* Wv    = (const float*)d_in[7];
    const float* bv    = (const float*)d_in[8];
    const float* Wo    = (const float*)d_in[9];
    float* out = (float*)d_out;

    const long ACTB = (long)NHW * NC;
    const long SB   = (long)NHW * NHW;
    const long WSZ  = (long)NC * NC;

    char* ws = (char*)d_ws;
    float* stats = (float*)ws;
    BF* wb = (BF*)(ws + 4096);
    BF* q  = wb + 4 * WSZ;
    BF* kk = q + NB * ACTB;
    BF* vT = kk + NB * ACTB;
    BF* R  = vT + NB * ACTB;
    BF* n = R;   // live: GN -> QKV GEMMs
    BF* S = R;   // live: attention chunks

    const size_t base_need = 4096ull + (size_t)4 * WSZ * 2 + (size_t)3 * NB * ACTB * 2;
    long sroom = (ws_size > base_need) ? (long)((ws_size - base_need) / (SB * 2)) : 1;
    int chunk = (int)(sroom < 1 ? 1 : (sroom > NB ? NB : sroom));
    while (NB % chunk) chunk--;              // 8,4,2,1

    // split-K PV partials (f32, [bz][kh][ACTB]) after S, if room
    float* Pf = (float*)(R + (long)chunk * SB);
    const size_t splitNeed = base_need + (size_t)chunk * SB * 2
                           + (size_t)chunk * 2 * ACTB * 4;
    const bool doSplit = (chunk >= 2) && (ws_size >= splitNeed);

    f2b_convert4<<<1024, 256, 0, stream>>>(Wq, Wk, Wv, Wo, wb);

    gn_stats<<<NB * NG, 256, 0, stream>>>(x, stats);
    gn_apply<<<dim3(NHW / 64, NC / 64, NB), 256, 0, stream>>>(x, gamma, beta, stats, n);

    gemm256<true, false, false, false><<<dim3(NC / 256, NHW / 256, NB), 512, 0, stream>>>(
        n, ACTB, wb + 0 * WSZ, 0, q, ACTB, bq, nullptr, nullptr, NHW, NC, NC, 1.0f, NC, NC);
    gemm256<true, false, false, false><<<dim3(NC / 256, NHW / 256, NB), 512, 0, stream>>>(
        n, ACTB, wb + 1 * WSZ, 0, kk, ACTB, bk, nullptr, nullptr, NHW, NC, NC, 1.0f, NC, NC);
    gemm256<true, true, false, false><<<dim3(NC / 256, NHW / 256, NB), 512, 0, stream>>>(
        n, ACTB, wb + 2 * WSZ, 0, vT, ACTB, bv, nullptr, nullptr, NHW, NC, NC, 1.0f, NC, NC);

    const float iscl = 0.044194173824159216f;  // 1/sqrt(512)
    for (int b0 = 0; b0 < NB; b0 += chunk) {
        gemm256<false, false, false, false><<<dim3(NHW / 256, NHW / 256, chunk), 512, 0, stream>>>(
            q + b0 * ACTB, ACTB, kk + b0 * ACTB, ACTB, S, SB, nullptr, nullptr, nullptr,
            NHW, NHW, NC, iscl, NC, NC);
        softmax4096<<<NHW * chunk, 256, 0, stream>>>(S);
        if (doSplit) {
            // PV split-K=2: z = 2*bz+kh, each half K=2048; f32 partials, then reduce
            gemm256<false, false, false, true><<<dim3(NC / 256, NHW / 256, chunk * 2), 512, 0, stream>>>(
                S, SB, vT + b0 * ACTB, ACTB, nullptr, ACTB, nullptr, nullptr, Pf,
                NHW, NC, NHW / 2, 1.0f, NHW, NHW);
            splitk_reduce<<<dim3((unsigned)(ACTB / 1024), chunk), 256, 0, stream>>>(
                Pf, q + b0 * ACTB, ACTB);
        } else if (chunk >= 4) {
            gemm256<false, false, false, false><<<dim3(NC / 256, NHW / 256, chunk), 512, 0, stream>>>(
                S, SB, vT + b0 * ACTB, ACTB, q + b0 * ACTB, ACTB, nullptr, nullptr, nullptr,
                NHW, NC, NHW, 1.0f, NHW, NHW);
        } else if (chunk == 2) {
            gemm128<false, false><<<dim3(NC / 128, NHW / 128, chunk), 256, 0, stream>>>(
                S, SB, vT + b0 * ACTB, ACTB, q + b0 * ACTB, ACTB, nullptr, NHW, NC, NHW, 1.0f);
        } else {
            gemm64<<<dim3(NC / 128, NHW / 64, chunk), 256, 0, stream>>>(
                S, SB, vT + b0 * ACTB, ACTB, q + b0 * ACTB, ACTB, NC, NHW, 1.0f);
        }
    }

    // final projection fused with transpose + residual add (writes f32 output)
    gemm256<false, true, true, false><<<dim3(NC / 256, NHW / 256, NB), 512, 0, stream>>>(
        q, ACTB, wb + 3 * WSZ, 0, nullptr, ACTB, nullptr, x, out, NHW, NC, NC, 1.0f, NC, NC);
}